// Round 10
// baseline (332.789 us; speedup 1.0000x reference)
//
#include <hip/hip_runtime.h>
#include <hip/hip_bf16.h>

// BloodFlowSkinAnalyzer — f32 in/out (verified r5). Out layout (floats):
//   flow[4]@0, sync[4]@4, color[4*64*3]@8, masks[4,64,1,128,128]@776,
//   naturalness[4]@4195080, temporal[4,32,64]@4195084
// ws: colsum[4096][4] floats @0.
// Both seg convs on MFMA bf16 16x16x32 (operand layouts HW-verified r7/r8).
// r10: software-pipelined tile loop (double-buffered in_bs, early load issue),
//      tile-invariant addressing hoisted, conv2 = 4 independent MFMA chains.

typedef __attribute__((ext_vector_type(8))) short bf16x8;
typedef __attribute__((ext_vector_type(4))) float f32x4;

#define NAT_OFF  4195080
#define TF_OFF   4195084

__device__ __forceinline__ unsigned short f2bf(float f) {   // RNE f32->bf16
    unsigned u = __float_as_uint(f);
    u += 0x7FFFu + ((u >> 16) & 1u);
    return (unsigned short)(u >> 16);
}
__device__ __forceinline__ float bf2f(unsigned short u) {
    return __uint_as_float((unsigned)u << 16);
}
__device__ __forceinline__ unsigned pack_bf2(float lo, float hi) {
    __hip_bfloat162 h2 = __float22bfloat162_rn(make_float2(lo, hi));
    return *reinterpret_cast<unsigned*>(&h2);   // .x in low 16 bits
}

// Fused seg: conv1(3->32,k3,p1) MFMA + conv2(32->16,k3,p1) MFMA +
// conv3(16->1,k1)+sigmoid + masked sums. Block = 4 of 64 16x16 tiles.
__global__ __launch_bounds__(256) void seg_kernel(
    const float* __restrict__ x,
    const float* __restrict__ w1f, const float* __restrict__ b1f,
    const float* __restrict__ w2f, const float* __restrict__ b2f,
    const float* __restrict__ w3f, const float* __restrict__ b3f,
    float* __restrict__ colsum, float* __restrict__ out)
{
    const int tid  = threadIdx.x;
    const int lane = tid & 63;
    const int wid  = tid >> 6;
    const int img  = blockIdx.x >> 4;        // b*64+t
    const int part = blockIdx.x & 15;        // 4 tiles per part

    __shared__ __align__(4)  unsigned short in_bs[2][1200]; // dbuf 3x20x20 bf16
    __shared__ __align__(16) unsigned short h1_s[12960];    // [(y*18+x)*40+oc]
    __shared__ float red[4][4];

    const int ocl = lane & 15;   // free idx: A-row / B-col
    const int g   = lane >> 4;   // k-group (8 k's each)

    // ---- conv1 B-frags (k = ic*9+ky*3+kx, w1 native [oc][k]); k>=27 -> 0 ----
    bf16x8 c1b0, c1b1;
    int offB[8];                 // per-lane in_bs element offsets for A gather
#pragma unroll
    for (int e = 0; e < 8; ++e) {
        int k = g * 8 + e;
        if (k < 27) {
            int ic = k / 9, r2 = k - ic * 9, ky = r2 / 3, kx = r2 - ky * 3;
            offB[e] = ic * 400 + ky * 20 + kx;
            c1b0[e] = (short)f2bf(w1f[(2 * ocl)     * 27 + k]);
            c1b1[e] = (short)f2bf(w1f[(2 * ocl + 1) * 27 + k]);
        } else {
            offB[e] = 0;
            c1b0[e] = 0; c1b1[e] = 0;
        }
    }
    const float b1_e = b1f[2 * ocl], b1_o = b1f[2 * ocl + 1];

    // ---- conv2 B-frags: 9 chunks c=(ky*3+kx), k=ic; w2 is [oc][ic][3][3] ----
    bf16x8 bfrag[9];
#pragma unroll
    for (int c = 0; c < 9; ++c) {
        bf16x8 t;
#pragma unroll
        for (int e = 0; e < 8; ++e)
            t[e] = (short)f2bf(w2f[(ocl * 32 + g * 8 + e) * 9 + c]);
        bfrag[c] = t;
    }
    const float b2_l = b2f[ocl];
    const float w3_l = w3f[ocl];
    const float b3v  = b3f[0];

    // ---- tile-invariant hoists ----
    // staging decomposition (<=5 slots per thread)
    int goff[5], rr[5], cc2[5], lidx[5];
#pragma unroll
    for (int s = 0; s < 5; ++s) {
        int idx = tid + 256 * s;
        int i2 = idx < 1200 ? idx : 0;
        int ic = i2 / 400, rem = i2 - ic * 400, r = rem / 20, c = rem - r * 20;
        goff[s] = ic * 16384 + r * 128 + c;
        rr[s] = r; cc2[s] = c; lidx[s] = idx;   // idx>=1200 -> skip
    }
    // conv1 group bases (grp = wid + gi*4)
    int baseA[6], wbase[6];
#pragma unroll
    for (int gi = 0; gi < 6; ++gi) {
        int grp = wid + gi * 4;
        int pos = grp * 16 + ocl;
        int hy = pos / 18, hx = pos - hy * 18;
        int b2_ = hy * 20 + hx;
        baseA[gi] = b2_ > 357 ? 357 : b2_;
        wbase[gi] = (grp * 16 + g * 4) * 40 + 2 * ocl;
    }
    // conv2 read base (immediate-offset reads off this)
    const unsigned short* hb = &h1_s[((wid * 4) * 18 + ocl) * 40 + g * 8];

    const float* xin = x + (size_t)img * 3 * 16384;
    float s0 = 0.f, s1 = 0.f, s2 = 0.f, sm = 0.f;

    // ---- prologue: stage tile 0 ----
    {
        const int tile = part * 4;
        const int r0 = (tile >> 3) * 16, c0 = (tile & 7) * 16;
        const float* xb = xin + (r0 - 2) * 128 + (c0 - 2);
        const bool inter = (r0 >= 16 && r0 <= 96 && c0 >= 16 && c0 <= 96);
#pragma unroll
        for (int s = 0; s < 5; ++s) {
            if (lidx[s] < 1200) {
                float vv = 0.f;
                if (inter || (((unsigned)(r0 - 2 + rr[s]) < 128u) &&
                              ((unsigned)(c0 - 2 + cc2[s]) < 128u)))
                    vv = xb[goff[s]];
                in_bs[0][lidx[s]] = f2bf(vv);
            }
        }
    }
    __syncthreads();

#pragma unroll
    for (int tt = 0; tt < 4; ++tt) {
        const int cur = tt & 1;
        const int tile = part * 4 + tt;
        const int r0 = (tile >> 3) * 16, c0 = (tile & 7) * 16;
        const bool interior = (r0 >= 16 && r0 <= 96 && c0 >= 16 && c0 <= 96);
        const unsigned short* inb = in_bs[cur];

        // ---- issue next tile's loads early (latency hides under conv1+2) ----
        float v[5];
        if (tt < 3) {
            const int tile_n = tile + 1;
            const int r0n = (tile_n >> 3) * 16, c0n = (tile_n & 7) * 16;
            const bool intn = (r0n >= 16 && r0n <= 96 && c0n >= 16 && c0n <= 96);
            const float* xbn = xin + (r0n - 2) * 128 + (c0n - 2);
#pragma unroll
            for (int s = 0; s < 5; ++s) {
                v[s] = 0.f;
                if (lidx[s] < 1200 &&
                    (intn || (((unsigned)(r0n - 2 + rr[s]) < 128u) &&
                              ((unsigned)(c0n - 2 + cc2[s]) < 128u))))
                    v[s] = xbn[goff[s]];
            }
        }

        // ---- conv1 MFMA: groups grp = wid + gi*4 < 21 ----
#pragma unroll
        for (int gi = 0; gi < 6; ++gi) {
            const int grp = wid + gi * 4;
            if (grp < 21) {                       // wave-uniform
                const unsigned short* ap = inb + baseA[gi];
                bf16x8 afrag;
#pragma unroll
                for (int e = 0; e < 8; ++e) afrag[e] = (short)ap[offB[e]];
                f32x4 d0 = {0.f, 0.f, 0.f, 0.f}, d1 = {0.f, 0.f, 0.f, 0.f};
                d0 = __builtin_amdgcn_mfma_f32_16x16x32_bf16(afrag, c1b0, d0, 0, 0, 0);
                d1 = __builtin_amdgcn_mfma_f32_16x16x32_bf16(afrag, c1b1, d1, 0, 0, 0);
                unsigned short* wp = &h1_s[wbase[gi]];
                const int p0 = grp * 16 + g * 4;
                if (interior) {
#pragma unroll
                    for (int r = 0; r < 4; ++r) {
                        if (grp < 20 || p0 + r < 324)
                            *reinterpret_cast<unsigned*>(wp + r * 40) =
                                pack_bf2(fmaxf(d0[r] + b1_e, 0.f),
                                         fmaxf(d1[r] + b1_o, 0.f));
                    }
                } else {
                    int hy2 = p0 / 18, hx2 = p0 - hy2 * 18;
#pragma unroll
                    for (int r = 0; r < 4; ++r) {
                        if (p0 + r < 324) {
                            bool valid = ((unsigned)(r0 - 1 + hy2) < 128u) &&
                                         ((unsigned)(c0 - 1 + hx2) < 128u);
                            float he = valid ? fmaxf(d0[r] + b1_e, 0.f) : 0.f;
                            float ho = valid ? fmaxf(d1[r] + b1_o, 0.f) : 0.f;
                            *reinterpret_cast<unsigned*>(wp + r * 40) = pack_bf2(he, ho);
                        }
                        ++hx2;
                        if (hx2 == 18) { hx2 = 0; ++hy2; }
                    }
                }
            }
        }
        __syncthreads();

        // ---- conv2: 36 MFMA as 4 independent chains, then epilogue ----
        f32x4 acc4[4];
#pragma unroll
        for (int q = 0; q < 4; ++q) acc4[q] = (f32x4){0.f, 0.f, 0.f, 0.f};
#pragma unroll
        for (int c = 0; c < 9; ++c) {
            const int ky = c / 3, kx = c - ky * 3;
#pragma unroll
            for (int q = 0; q < 4; ++q) {
                bf16x8 afrag = *reinterpret_cast<const bf16x8*>(
                    hb + ((q + ky) * 18 + kx) * 40);
                acc4[q] = __builtin_amdgcn_mfma_f32_16x16x32_bf16(
                    afrag, bfrag[c], acc4[q], 0, 0, 0);
            }
        }
#pragma unroll
        for (int q = 0; q < 4; ++q) {
            const int s = wid * 4 + q;
            float m0 = fmaxf(acc4[q][0] + b2_l, 0.f) * w3_l;
            float m1 = fmaxf(acc4[q][1] + b2_l, 0.f) * w3_l;
            float m2 = fmaxf(acc4[q][2] + b2_l, 0.f) * w3_l;
            float m3 = fmaxf(acc4[q][3] + b2_l, 0.f) * w3_l;
#pragma unroll
            for (int mk2 = 1; mk2 < 16; mk2 <<= 1) {
                m0 += __shfl_xor(m0, mk2);
                m1 += __shfl_xor(m1, mk2);
                m2 += __shfl_xor(m2, mk2);
                m3 += __shfl_xor(m3, mk2);
            }
            if (ocl < 4) {
                int r = lane & 3;
                float mm = (r == 0) ? m0 : (r == 1) ? m1 : (r == 2) ? m2 : m3;
                float msk = 1.f / (1.f + __expf(-(mm + b3v)));
                int xw = g * 4 + r;
                out[776 + (size_t)img * 16384 + (size_t)(r0 + s) * 128 + (c0 + xw)] = msk;
                float f0  = bf2f(inb[      (s + 2) * 20 + (xw + 2)]);
                float f1v = bf2f(inb[400 + (s + 2) * 20 + (xw + 2)]);
                float f2v = bf2f(inb[800 + (s + 2) * 20 + (xw + 2)]);
                s0 = fmaf(msk, f0, s0);
                s1 = fmaf(msk, f1v, s1);
                s2 = fmaf(msk, f2v, s2);
                sm += msk;
            }
        }

        // ---- write next tile's halo into the other buffer ----
        if (tt < 3) {
#pragma unroll
            for (int s = 0; s < 5; ++s)
                if (lidx[s] < 1200) in_bs[cur ^ 1][lidx[s]] = f2bf(v[s]);
        }
        __syncthreads();
    }

    // ---- block reduction of the 4 sums ----
#pragma unroll
    for (int off = 32; off > 0; off >>= 1) {
        s0 += __shfl_down(s0, off);
        s1 += __shfl_down(s1, off);
        s2 += __shfl_down(s2, off);
        sm += __shfl_down(sm, off);
    }
    if (lane == 0) { red[wid][0] = s0; red[wid][1] = s1; red[wid][2] = s2; red[wid][3] = sm; }
    __syncthreads();
    if (tid < 4) {
        float s = red[0][tid] + red[1][tid] + red[2][tid] + red[3][tid];
        colsum[(size_t)blockIdx.x * 4 + tid] = s;   // [img][part][4]
    }
}

// Tail: color signals, ct convs, ta convs, pooling, FC, stats. 1 block / b.
__global__ __launch_bounds__(256) void tail_kernel(
    const float* __restrict__ colsum,
    const float* __restrict__ cw1, const float* __restrict__ cb1,
    const float* __restrict__ cw2, const float* __restrict__ cb2,
    const float* __restrict__ cw3, const float* __restrict__ cb3,
    const float* __restrict__ tw1, const float* __restrict__ tb1,
    const float* __restrict__ tw2, const float* __restrict__ tb2,
    const float* __restrict__ tw3, const float* __restrict__ tb3,
    const float* __restrict__ fw1, const float* __restrict__ fb1,
    const float* __restrict__ fw2, const float* __restrict__ fb2,
    const float* __restrict__ fw3, const float* __restrict__ fb3,
    float* __restrict__ out)
{
    const int b = blockIdx.x, tid = threadIdx.x;
    __shared__ float tmp[64][4];
    __shared__ float cs_s[3 * 64];
    __shared__ float e3s[3 * 64];
    __shared__ float f1[32 * 64];
    __shared__ float f2[64 * 64];
    __shared__ float tf[32 * 64];
    __shared__ float wA[6144];
    __shared__ float pooled[32], g1[64], g2[32], sca[8];

    {
        int t = tid >> 2, slot = tid & 3;
        const float* pp = colsum + (size_t)((b * 64 + t) * 16) * 4 + slot;
        float s = 0.f;
#pragma unroll
        for (int p = 0; p < 16; ++p) s += pp[p * 4];
        tmp[t][slot] = s;
    }
    __syncthreads();
    for (int idx = tid; idx < 192; idx += 256) {
        int c = idx >> 6, t = idx & 63;
        float v = tmp[t][c] / (tmp[t][3] + 1e-8f);
        cs_s[idx] = v;
        out[8 + (b * 64 + t) * 3 + c] = v;
    }
    __syncthreads();

    if (tid < 64) {
        int t = tid;
        float c0v = cs_s[t], c1v = cs_s[64 + t], c2v = cs_s[128 + t];
        float e1[16];
#pragma unroll
        for (int o = 0; o < 16; ++o)
            e1[o] = fmaxf(cb1[o] + cw1[o * 3 + 0] * c0v + cw1[o * 3 + 1] * c1v
                                 + cw1[o * 3 + 2] * c2v, 0.f);
        float e2[8];
#pragma unroll
        for (int o = 0; o < 8; ++o) {
            float a = cb2[o];
#pragma unroll
            for (int i2 = 0; i2 < 16; ++i2) a += cw2[o * 16 + i2] * e1[i2];
            e2[o] = fmaxf(a, 0.f);
        }
#pragma unroll
        for (int o = 0; o < 3; ++o) {
            float a = cb3[o];
#pragma unroll
            for (int i2 = 0; i2 < 8; ++i2) a += cw3[o * 8 + i2] * e2[i2];
            e3s[o * 64 + t] = a;   // no relu on last ct conv
        }
    }
    __syncthreads();

    for (int idx = tid; idx < 2048; idx += 256) {
        int o = idx >> 6, t = idx & 63;
        float a = tb1[o];
#pragma unroll
        for (int ic = 0; ic < 3; ++ic)
#pragma unroll
            for (int k = 0; k < 3; ++k) {
                int ttk = t + k - 1;
                if ((unsigned)ttk < 64u) a += e3s[ic * 64 + ttk] * tw1[(o * 3 + ic) * 3 + k];
            }
        f1[idx] = fmaxf(a, 0.f);
    }
    for (int i2 = tid; i2 < 6144; i2 += 256) wA[i2] = tw2[i2];
    __syncthreads();

    for (int idx = tid; idx < 4096; idx += 256) {
        int o = idx >> 6, t = idx & 63;
        float a = tb2[o];
        for (int ic = 0; ic < 32; ++ic) {
            const float* wp = &wA[(o * 32 + ic) * 3];
            int base = ic * 64 + t;
            if (t > 0)  a += f1[base - 1] * wp[0];
            a += f1[base] * wp[1];
            if (t < 63) a += f1[base + 1] * wp[2];
        }
        f2[idx] = fmaxf(a, 0.f);
    }
    __syncthreads();
    for (int i2 = tid; i2 < 6144; i2 += 256) wA[i2] = tw3[i2];
    __syncthreads();

    for (int idx = tid; idx < 2048; idx += 256) {
        int o = idx >> 6, t = idx & 63;
        float a = tb3[o];
        for (int ic = 0; ic < 64; ++ic) {
            const float* wp = &wA[(o * 64 + ic) * 3];
            int base = ic * 64 + t;
            if (t > 0)  a += f2[base - 1] * wp[0];
            a += f2[base] * wp[1];
            if (t < 63) a += f2[base + 1] * wp[2];
        }
        float r = fmaxf(a, 0.f);
        tf[idx] = r;
        out[TF_OFF + (b * 32 + o) * 64 + t] = r;
    }
    __syncthreads();

    if (tid < 32) {
        float s = 0.f;
        for (int t = 0; t < 64; ++t) s += tf[tid * 64 + t];
        pooled[tid] = s * (1.f / 64.f);
    }
    __syncthreads();

    if (tid < 64) {
        float a = fb1[tid];
#pragma unroll
        for (int i2 = 0; i2 < 32; ++i2) a += pooled[i2] * fw1[tid * 32 + i2];
        g1[tid] = fmaxf(a, 0.f);
    }
    __syncthreads();
    if (tid < 32) {
        float a = fb2[tid];
        for (int i2 = 0; i2 < 64; ++i2) a += g1[i2] * fw2[tid * 64 + i2];
        g2[tid] = fmaxf(a, 0.f);
    }
    __syncthreads();
    if (tid == 0) {
        float a = fb3[0];
        for (int i2 = 0; i2 < 32; ++i2) a += g2[i2] * fw3[i2];
        float flow = 1.f / (1.f + expf(-a));
        sca[0] = flow;
        out[b] = flow;
    }
    if (tid >= 4 && tid < 7) {
        int c = tid - 4;
        float mu = 0.f;
        for (int t = 0; t < 64; ++t) mu += cs_s[c * 64 + t];
        mu *= (1.f / 64.f);
        float v = 0.f;
        for (int t = 0; t < 64; ++t) { float d = cs_s[c * 64 + t] - mu; v += d * d; }
        sca[1 + c] = sqrtf(v / 63.f);
    }
    __syncthreads();
    if (tid == 0) {
        float s0 = sca[1], s1 = sca[2], s2 = sca[3];
        float mu = (s0 + s1 + s2) * (1.f / 3.f);
        float var = ((s0 - mu) * (s0 - mu) + (s1 - mu) * (s1 - mu) + (s2 - mu) * (s2 - mu)) * 0.5f;
        float sy = 1.f / (1.f + expf(var));     // sigmoid(-var)
        out[4 + b] = sy;
        out[NAT_OFF + b] = (sca[0] + sy) * 0.5f;
    }
}

extern "C" void kernel_launch(void* const* d_in, const int* in_sizes, int n_in,
                              void* d_out, int out_size, void* d_ws, size_t ws_size,
                              hipStream_t stream)
{
    float* wsf = (float*)d_ws;
    float* out = (float*)d_out;

    seg_kernel<<<dim3(4096), 256, 0, stream>>>((const float*)d_in[0],
        (const float*)d_in[1], (const float*)d_in[2],
        (const float*)d_in[3], (const float*)d_in[4],
        (const float*)d_in[5], (const float*)d_in[6],
        wsf, out);

    tail_kernel<<<dim3(4), 256, 0, stream>>>(wsf,
        (const float*)d_in[7],  (const float*)d_in[8],
        (const float*)d_in[9],  (const float*)d_in[10],
        (const float*)d_in[11], (const float*)d_in[12],
        (const float*)d_in[13], (const float*)d_in[14],
        (const float*)d_in[15], (const float*)d_in[16],
        (const float*)d_in[17], (const float*)d_in[18],
        (const float*)d_in[19], (const float*)d_in[20],
        (const float*)d_in[21], (const float*)d_in[22],
        (const float*)d_in[23], (const float*)d_in[24],
        out);
}

// Round 11
// 245.373 us; speedup vs baseline: 1.3563x; 1.3563x over previous
//
#include <hip/hip_runtime.h>
#include <hip/hip_bf16.h>

// BloodFlowSkinAnalyzer — f32 in/out (verified r5). Out layout (floats):
//   flow[4]@0, sync[4]@4, color[4*64*3]@8, masks[4,64,1,128,128]@776,
//   naturalness[4]@4195080, temporal[4,32,64]@4195084
// ws: colsum[4096][4] floats @0.
// Both seg convs on MFMA bf16 16x16x32 (operand layouts HW-verified r7/r8).
// r11: r9 structure (r10's dbuf reverted — VGPR regression) + conv2 operand
//      swap (D=[oc][x] -> conv3 reduce = 4 FMA + 2 shfl, was 16 shfl) +
//      4 independent MFMA chains. Tail: 1024 thr + scalar weight loads.

typedef __attribute__((ext_vector_type(8))) short bf16x8;
typedef __attribute__((ext_vector_type(4))) float f32x4;

#define NAT_OFF  4195080
#define TF_OFF   4195084

__device__ __forceinline__ unsigned short f2bf(float f) {   // RNE f32->bf16
    unsigned u = __float_as_uint(f);
    u += 0x7FFFu + ((u >> 16) & 1u);
    return (unsigned short)(u >> 16);
}
__device__ __forceinline__ float bf2f(unsigned short u) {
    return __uint_as_float((unsigned)u << 16);
}
__device__ __forceinline__ unsigned pack_bf2(float lo, float hi) {
    __hip_bfloat162 h2 = __float22bfloat162_rn(make_float2(lo, hi));
    return *reinterpret_cast<unsigned*>(&h2);   // .x in low 16 bits
}

// Fused seg: conv1(3->32,k3,p1) MFMA + conv2(32->16,k3,p1) MFMA +
// conv3(16->1,k1)+sigmoid + masked sums. Block = 4 of 64 16x16 tiles.
__global__ __launch_bounds__(256) void seg_kernel(
    const float* __restrict__ x,
    const float* __restrict__ w1f, const float* __restrict__ b1f,
    const float* __restrict__ w2f, const float* __restrict__ b2f,
    const float* __restrict__ w3f, const float* __restrict__ b3f,
    float* __restrict__ colsum, float* __restrict__ out)
{
    const int tid  = threadIdx.x;
    const int lane = tid & 63;
    const int wid  = tid >> 6;
    const int img  = blockIdx.x >> 4;        // b*64+t
    const int part = blockIdx.x & 15;        // 4 tiles per part

    __shared__ __align__(4)  unsigned short in_bs[1200];  // 3x20x20 bf16 halo
    __shared__ __align__(16) unsigned short h1_s[12960];  // [(y*18+x)*40+oc]
    __shared__ float red[4][4];

    const int ocl = lane & 15;   // free idx
    const int g   = lane >> 4;   // k-group (8 k's each)

    // ---- conv1 B-frags (k = ic*9+ky*3+kx, w1 native [oc][k]); k>=27 -> 0 ----
    bf16x8 c1b0, c1b1;
    int offB[8];                 // per-lane in_bs element offsets for A gather
#pragma unroll
    for (int e = 0; e < 8; ++e) {
        int k = g * 8 + e;
        if (k < 27) {
            int ic = k / 9, r2 = k - ic * 9, ky = r2 / 3, kx = r2 - ky * 3;
            offB[e] = ic * 400 + ky * 20 + kx;
            c1b0[e] = (short)f2bf(w1f[(2 * ocl)     * 27 + k]);
            c1b1[e] = (short)f2bf(w1f[(2 * ocl + 1) * 27 + k]);
        } else {
            offB[e] = 0;
            c1b0[e] = 0; c1b1[e] = 0;
        }
    }
    const float b1_e = b1f[2 * ocl], b1_o = b1f[2 * ocl + 1];

    // ---- conv2 W-frags (used as MFMA *A* operand after swap) ----
    bf16x8 bfrag[9];
#pragma unroll
    for (int c = 0; c < 9; ++c) {
        bf16x8 t;
#pragma unroll
        for (int e = 0; e < 8; ++e)
            t[e] = (short)f2bf(w2f[(ocl * 32 + g * 8 + e) * 9 + c]);
        bfrag[c] = t;
    }
    // conv3 per-lane constants for oc = g*4+r (D rows after swap)
    float b2v[4], w3v[4];
#pragma unroll
    for (int r = 0; r < 4; ++r) { b2v[r] = b2f[g * 4 + r]; w3v[r] = w3f[g * 4 + r]; }
    const float b3v = b3f[0];

    const float* xin = x + (size_t)img * 3 * 16384;
    float s0 = 0.f, s1 = 0.f, s2 = 0.f, sm = 0.f;

    for (int tt = 0; tt < 4; ++tt) {
        const int tile = part * 4 + tt;
        const int r0 = (tile >> 3) * 16, c0 = (tile & 7) * 16;
        const bool interior = (r0 >= 16 && r0 <= 96 && c0 >= 16 && c0 <= 96);
        __syncthreads();                     // prev-tile readers done

        // ---- stage 20x20x3 halo as bf16 ----
        if (interior) {
            const float* xb = xin + (r0 - 2) * 128 + (c0 - 2);
            for (int idx = tid; idx < 1200; idx += 256) {
                int ic = idx / 400, rem = idx - ic * 400;
                int r = rem / 20, cc = rem - r * 20;
                in_bs[idx] = f2bf(xb[ic * 16384 + r * 128 + cc]);
            }
        } else {
            for (int idx = tid; idx < 1200; idx += 256) {
                int ic = idx / 400, rem = idx - ic * 400;
                int r = rem / 20, cc = rem - r * 20;
                int gr = r0 - 2 + r, gc = c0 - 2 + cc;
                float vv = 0.f;
                if ((unsigned)gr < 128u && (unsigned)gc < 128u)
                    vv = xin[ic * 16384 + gr * 128 + gc];
                in_bs[idx] = f2bf(vv);
            }
        }
        __syncthreads();

        // ---- conv1 MFMA: 21 groups of 16 positions over 4 waves ----
        for (int grp = wid; grp < 21; grp += 4) {
            int pos = grp * 16 + ocl;                 // A row
            int hy = pos / 18, hx = pos - hy * 18;
            int base = hy * 20 + hx;
            base = base > 357 ? 357 : base;           // clamp tail-group lanes
            bf16x8 afrag;
#pragma unroll
            for (int e = 0; e < 8; ++e)
                afrag[e] = (short)in_bs[base + offB[e]];
            f32x4 d0 = {0.f, 0.f, 0.f, 0.f}, d1 = {0.f, 0.f, 0.f, 0.f};
            d0 = __builtin_amdgcn_mfma_f32_16x16x32_bf16(afrag, c1b0, d0, 0, 0, 0);
            d1 = __builtin_amdgcn_mfma_f32_16x16x32_bf16(afrag, c1b1, d1, 0, 0, 0);
            int p0 = grp * 16 + g * 4;
            if (interior) {
#pragma unroll
                for (int r = 0; r < 4; ++r) {
                    int p2 = p0 + r;
                    if (p2 < 324) {
                        unsigned pk = pack_bf2(fmaxf(d0[r] + b1_e, 0.f),
                                               fmaxf(d1[r] + b1_o, 0.f));
                        *reinterpret_cast<unsigned*>(&h1_s[p2 * 40 + 2 * ocl]) = pk;
                    }
                }
            } else {
                int hy2 = p0 / 18, hx2 = p0 - hy2 * 18;
#pragma unroll
                for (int r = 0; r < 4; ++r) {
                    int p2 = p0 + r;
                    if (p2 < 324) {
                        bool valid = ((unsigned)(r0 - 1 + hy2) < 128u) &&
                                     ((unsigned)(c0 - 1 + hx2) < 128u);
                        float he = valid ? fmaxf(d0[r] + b1_e, 0.f) : 0.f;
                        float ho = valid ? fmaxf(d1[r] + b1_o, 0.f) : 0.f;
                        *reinterpret_cast<unsigned*>(&h1_s[p2 * 40 + 2 * ocl]) =
                            pack_bf2(he, ho);
                    }
                    ++hx2;
                    if (hx2 == 18) { hx2 = 0; ++hy2; }
                }
            }
        }
        __syncthreads();

        // ---- conv2: swapped operands (A=weights, B=h1) -> D[oc][x].
        //      4 independent chains (output rows s = wid*4 + q).
        const unsigned short* hb = &h1_s[((wid * 4) * 18 + ocl) * 40 + g * 8];
        f32x4 acc4[4];
#pragma unroll
        for (int q = 0; q < 4; ++q) acc4[q] = (f32x4){0.f, 0.f, 0.f, 0.f};
#pragma unroll
        for (int c = 0; c < 9; ++c) {
            const int ky = c / 3, kx = c - ky * 3;
#pragma unroll
            for (int q = 0; q < 4; ++q) {
                bf16x8 bfr = *reinterpret_cast<const bf16x8*>(
                    hb + ((q + ky) * 18 + kx) * 40);
                acc4[q] = __builtin_amdgcn_mfma_f32_16x16x32_bf16(
                    bfrag[c], bfr, acc4[q], 0, 0, 0);
            }
        }
        // conv3: lane holds P[oc=g*4+r][x=ocl]; reduce 4 in-lane + across g
#pragma unroll
        for (int q = 0; q < 4; ++q) {
            const int s = wid * 4 + q;
            float part3 = 0.f;
#pragma unroll
            for (int r = 0; r < 4; ++r)
                part3 = fmaf(fmaxf(acc4[q][r] + b2v[r], 0.f), w3v[r], part3);
            part3 += __shfl_xor(part3, 16);
            part3 += __shfl_xor(part3, 32);
            if (lane < 16) {
                int xw = lane;
                float msk = 1.f / (1.f + __expf(-(part3 + b3v)));
                out[776 + (size_t)img * 16384 + (size_t)(r0 + s) * 128 + (c0 + xw)] = msk;
                float f0  = bf2f(in_bs[      (s + 2) * 20 + (xw + 2)]);
                float f1v = bf2f(in_bs[400 + (s + 2) * 20 + (xw + 2)]);
                float f2v = bf2f(in_bs[800 + (s + 2) * 20 + (xw + 2)]);
                s0 = fmaf(msk, f0, s0);
                s1 = fmaf(msk, f1v, s1);
                s2 = fmaf(msk, f2v, s2);
                sm += msk;
            }
        }
    }

    // ---- block reduction of the 4 sums ----
#pragma unroll
    for (int off = 32; off > 0; off >>= 1) {
        s0 += __shfl_down(s0, off);
        s1 += __shfl_down(s1, off);
        s2 += __shfl_down(s2, off);
        sm += __shfl_down(sm, off);
    }
    if (lane == 0) { red[wid][0] = s0; red[wid][1] = s1; red[wid][2] = s2; red[wid][3] = sm; }
    __syncthreads();
    if (tid < 4) {
        float s = red[0][tid] + red[1][tid] + red[2][tid] + red[3][tid];
        colsum[(size_t)blockIdx.x * 4 + tid] = s;   // [img][part][4]
    }
}

// Tail: 1024 threads; weight reads wave-uniform (o const per wave -> s_load).
__global__ __launch_bounds__(1024) void tail_kernel(
    const float* __restrict__ colsum,
    const float* __restrict__ cw1, const float* __restrict__ cb1,
    const float* __restrict__ cw2, const float* __restrict__ cb2,
    const float* __restrict__ cw3, const float* __restrict__ cb3,
    const float* __restrict__ tw1, const float* __restrict__ tb1,
    const float* __restrict__ tw2, const float* __restrict__ tb2,
    const float* __restrict__ tw3, const float* __restrict__ tb3,
    const float* __restrict__ fw1, const float* __restrict__ fb1,
    const float* __restrict__ fw2, const float* __restrict__ fb2,
    const float* __restrict__ fw3, const float* __restrict__ fb3,
    float* __restrict__ out)
{
    const int b = blockIdx.x, tid = threadIdx.x;
    __shared__ float tmp[64][4];
    __shared__ float cs_s[3 * 64];
    __shared__ float e3s[3 * 64];
    __shared__ float f1[32 * 64];
    __shared__ float f2[64 * 64];
    __shared__ float tf[32 * 64];
    __shared__ float pooled[32], g1[64], g2[32], sca[8];

    if (tid < 256) {
        int t = tid >> 2, slot = tid & 3;
        const float* pp = colsum + (size_t)((b * 64 + t) * 16) * 4 + slot;
        float s = 0.f;
#pragma unroll
        for (int p = 0; p < 16; ++p) s += pp[p * 4];
        tmp[t][slot] = s;
    }
    __syncthreads();
    if (tid < 192) {
        int c = tid >> 6, t = tid & 63;
        float v = tmp[t][c] / (tmp[t][3] + 1e-8f);
        cs_s[tid] = v;
        out[8 + (b * 64 + t) * 3 + c] = v;
    }
    __syncthreads();

    if (tid < 64) {
        int t = tid;
        float c0v = cs_s[t], c1v = cs_s[64 + t], c2v = cs_s[128 + t];
        float e1[16];
#pragma unroll
        for (int o = 0; o < 16; ++o)
            e1[o] = fmaxf(cb1[o] + cw1[o * 3 + 0] * c0v + cw1[o * 3 + 1] * c1v
                                 + cw1[o * 3 + 2] * c2v, 0.f);
        float e2[8];
#pragma unroll
        for (int o = 0; o < 8; ++o) {
            float a = cb2[o];
#pragma unroll
            for (int i2 = 0; i2 < 16; ++i2) a += cw2[o * 16 + i2] * e1[i2];
            e2[o] = fmaxf(a, 0.f);
        }
#pragma unroll
        for (int o = 0; o < 3; ++o) {
            float a = cb3[o];
#pragma unroll
            for (int i2 = 0; i2 < 8; ++i2) a += cw3[o * 8 + i2] * e2[i2];
            e3s[o * 64 + t] = a;   // no relu on last ct conv
        }
    }
    __syncthreads();

    // ta1: 3->32 k3 p1 (2048 outputs, o = wave-uniform)
    {
        int o = tid >> 6, t = tid & 63;
#pragma unroll
        for (int h = 0; h < 2; ++h) {
            int oo = o + 16 * h;
            float a = tb1[oo];
#pragma unroll
            for (int ic = 0; ic < 3; ++ic)
#pragma unroll
                for (int k = 0; k < 3; ++k) {
                    int ttk = t + k - 1;
                    if ((unsigned)ttk < 64u)
                        a += e3s[ic * 64 + ttk] * tw1[(oo * 3 + ic) * 3 + k];
                }
            f1[oo * 64 + t] = fmaxf(a, 0.f);
        }
    }
    __syncthreads();

    // ta2: 32->64 k3 p1 (4096 outputs)
    {
        int o = tid >> 6, t = tid & 63;
#pragma unroll
        for (int h = 0; h < 4; ++h) {
            int oo = o + 16 * h;
            float a = tb2[oo];
            for (int ic = 0; ic < 32; ++ic) {
                const float* wp = tw2 + (oo * 32 + ic) * 3;   // scalar loads
                int base = ic * 64 + t;
                if (t > 0)  a += f1[base - 1] * wp[0];
                a += f1[base] * wp[1];
                if (t < 63) a += f1[base + 1] * wp[2];
            }
            f2[oo * 64 + t] = fmaxf(a, 0.f);
        }
    }
    __syncthreads();

    // ta3: 64->32 k3 p1 (+ temporal_features out)
    {
        int o = tid >> 6, t = tid & 63;
#pragma unroll
        for (int h = 0; h < 2; ++h) {
            int oo = o + 16 * h;
            float a = tb3[oo];
            for (int ic = 0; ic < 64; ++ic) {
                const float* wp = tw3 + (oo * 64 + ic) * 3;   // scalar loads
                int base = ic * 64 + t;
                if (t > 0)  a += f2[base - 1] * wp[0];
                a += f2[base] * wp[1];
                if (t < 63) a += f2[base + 1] * wp[2];
            }
            float r = fmaxf(a, 0.f);
            tf[oo * 64 + t] = r;
            out[TF_OFF + (b * 32 + oo) * 64 + t] = r;
        }
    }
    __syncthreads();

    if (tid < 32) {
        float s = 0.f;
        for (int t = 0; t < 64; ++t) s += tf[tid * 64 + t];
        pooled[tid] = s * (1.f / 64.f);
    }
    __syncthreads();

    if (tid < 64) {
        float a = fb1[tid];
#pragma unroll
        for (int i2 = 0; i2 < 32; ++i2) a += pooled[i2] * fw1[tid * 32 + i2];
        g1[tid] = fmaxf(a, 0.f);
    }
    __syncthreads();
    if (tid < 32) {
        float a = fb2[tid];
        for (int i2 = 0; i2 < 64; ++i2) a += g1[i2] * fw2[tid * 64 + i2];
        g2[tid] = fmaxf(a, 0.f);
    }
    __syncthreads();
    if (tid == 0) {
        float a = fb3[0];
        for (int i2 = 0; i2 < 32; ++i2) a += g2[i2] * fw3[i2];
        float flow = 1.f / (1.f + expf(-a));
        sca[0] = flow;
        out[b] = flow;
    }
    if (tid >= 4 && tid < 7) {
        int c = tid - 4;
        float mu = 0.f;
        for (int t = 0; t < 64; ++t) mu += cs_s[c * 64 + t];
        mu *= (1.f / 64.f);
        float v = 0.f;
        for (int t = 0; t < 64; ++t) { float d = cs_s[c * 64 + t] - mu; v += d * d; }
        sca[1 + c] = sqrtf(v / 63.f);
    }
    __syncthreads();
    if (tid == 0) {
        float s0 = sca[1], s1 = sca[2], s2 = sca[3];
        float mu = (s0 + s1 + s2) * (1.f / 3.f);
        float var = ((s0 - mu) * (s0 - mu) + (s1 - mu) * (s1 - mu) + (s2 - mu) * (s2 - mu)) * 0.5f;
        float sy = 1.f / (1.f + expf(var));     // sigmoid(-var)
        out[4 + b] = sy;
        out[NAT_OFF + b] = (sca[0] + sy) * 0.5f;
    }
}

extern "C" void kernel_launch(void* const* d_in, const int* in_sizes, int n_in,
                              void* d_out, int out_size, void* d_ws, size_t ws_size,
                              hipStream_t stream)
{
    float* wsf = (float*)d_ws;
    float* out = (float*)d_out;

    seg_kernel<<<dim3(4096), 256, 0, stream>>>((const float*)d_in[0],
        (const float*)d_in[1], (const float*)d_in[2],
        (const float*)d_in[3], (const float*)d_in[4],
        (const float*)d_in[5], (const float*)d_in[6],
        wsf, out);

    tail_kernel<<<dim3(4), 1024, 0, stream>>>(wsf,
        (const float*)d_in[7],  (const float*)d_in[8],
        (const float*)d_in[9],  (const float*)d_in[10],
        (const float*)d_in[11], (const float*)d_in[12],
        (const float*)d_in[13], (const float*)d_in[14],
        (const float*)d_in[15], (const float*)d_in[16],
        (const float*)d_in[17], (const float*)d_in[18],
        (const float*)d_in[19], (const float*)d_in[20],
        (const float*)d_in[21], (const float*)d_in[22],
        (const float*)d_in[23], (const float*)d_in[24],
        out);
}

// Round 12
// 195.748 us; speedup vs baseline: 1.7001x; 1.2535x over previous
//
#include <hip/hip_runtime.h>
#include <hip/hip_bf16.h>

// BloodFlowSkinAnalyzer — f32 in/out (verified r5). Out layout (floats):
//   flow[4]@0, sync[4]@4, color[4*64*3]@8, masks[4,64,1,128,128]@776,
//   naturalness[4]@4195080, temporal[4,32,64]@4195084
// ws: colsum[4096][4] floats @0.
// Both seg convs on MFMA bf16 16x16x32 (operand layouts HW-verified r7/r8).
// r12: tail ta2/ta3 vectorized (b128 + lane-shfl halo, was 12 scalar LDS
//      reads per output); seg interior staging in f32-pairs (cvt_pk + b32).

typedef __attribute__((ext_vector_type(8))) short bf16x8;
typedef __attribute__((ext_vector_type(4))) float f32x4;

#define NAT_OFF  4195080
#define TF_OFF   4195084

__device__ __forceinline__ unsigned short f2bf(float f) {   // RNE f32->bf16
    unsigned u = __float_as_uint(f);
    u += 0x7FFFu + ((u >> 16) & 1u);
    return (unsigned short)(u >> 16);
}
__device__ __forceinline__ float bf2f(unsigned short u) {
    return __uint_as_float((unsigned)u << 16);
}
__device__ __forceinline__ unsigned pack_bf2(float lo, float hi) {
    __hip_bfloat162 h2 = __float22bfloat162_rn(make_float2(lo, hi));
    return *reinterpret_cast<unsigned*>(&h2);   // .x in low 16 bits
}

// Fused seg: conv1(3->32,k3,p1) MFMA + conv2(32->16,k3,p1) MFMA +
// conv3(16->1,k1)+sigmoid + masked sums. Block = 4 of 64 16x16 tiles.
__global__ __launch_bounds__(256) void seg_kernel(
    const float* __restrict__ x,
    const float* __restrict__ w1f, const float* __restrict__ b1f,
    const float* __restrict__ w2f, const float* __restrict__ b2f,
    const float* __restrict__ w3f, const float* __restrict__ b3f,
    float* __restrict__ colsum, float* __restrict__ out)
{
    const int tid  = threadIdx.x;
    const int lane = tid & 63;
    const int wid  = tid >> 6;
    const int img  = blockIdx.x >> 4;        // b*64+t
    const int part = blockIdx.x & 15;        // 4 tiles per part

    __shared__ __align__(4)  unsigned short in_bs[1200];  // 3x20x20 bf16 halo
    __shared__ __align__(16) unsigned short h1_s[12960];  // [(y*18+x)*40+oc]
    __shared__ float red[4][4];

    const int ocl = lane & 15;   // free idx
    const int g   = lane >> 4;   // k-group (8 k's each)

    // ---- conv1 B-frags (k = ic*9+ky*3+kx, w1 native [oc][k]); k>=27 -> 0 ----
    bf16x8 c1b0, c1b1;
    int offB[8];                 // per-lane in_bs element offsets for A gather
#pragma unroll
    for (int e = 0; e < 8; ++e) {
        int k = g * 8 + e;
        if (k < 27) {
            int ic = k / 9, r2 = k - ic * 9, ky = r2 / 3, kx = r2 - ky * 3;
            offB[e] = ic * 400 + ky * 20 + kx;
            c1b0[e] = (short)f2bf(w1f[(2 * ocl)     * 27 + k]);
            c1b1[e] = (short)f2bf(w1f[(2 * ocl + 1) * 27 + k]);
        } else {
            offB[e] = 0;
            c1b0[e] = 0; c1b1[e] = 0;
        }
    }
    const float b1_e = b1f[2 * ocl], b1_o = b1f[2 * ocl + 1];

    // ---- conv2 W-frags (MFMA A operand after swap) ----
    bf16x8 bfrag[9];
#pragma unroll
    for (int c = 0; c < 9; ++c) {
        bf16x8 t;
#pragma unroll
        for (int e = 0; e < 8; ++e)
            t[e] = (short)f2bf(w2f[(ocl * 32 + g * 8 + e) * 9 + c]);
        bfrag[c] = t;
    }
    // conv3 per-lane constants for oc = g*4+r (D rows after swap)
    float b2v[4], w3v[4];
#pragma unroll
    for (int r = 0; r < 4; ++r) { b2v[r] = b2f[g * 4 + r]; w3v[r] = w3f[g * 4 + r]; }
    const float b3v = b3f[0];

    const float* xin = x + (size_t)img * 3 * 16384;
    float s0 = 0.f, s1 = 0.f, s2 = 0.f, sm = 0.f;

    for (int tt = 0; tt < 4; ++tt) {
        const int tile = part * 4 + tt;
        const int r0 = (tile >> 3) * 16, c0 = (tile & 7) * 16;
        const bool interior = (r0 >= 16 && r0 <= 96 && c0 >= 16 && c0 <= 96);
        __syncthreads();                     // prev-tile readers done

        // ---- stage 20x20x3 halo as bf16 ----
        if (interior) {                      // pair-packed: b64 load + b32 write
            const float* xb = xin + (r0 - 2) * 128 + (c0 - 2);
            for (int p = tid; p < 600; p += 256) {
                int ic = p / 200, rem = p - ic * 200;
                int r = rem / 10, cp = rem - r * 10;
                float2 v = *reinterpret_cast<const float2*>(
                    xb + ic * 16384 + r * 128 + cp * 2);
                *reinterpret_cast<unsigned*>(&in_bs[ic * 400 + r * 20 + cp * 2]) =
                    pack_bf2(v.x, v.y);
            }
        } else {
            for (int idx = tid; idx < 1200; idx += 256) {
                int ic = idx / 400, rem = idx - ic * 400;
                int r = rem / 20, cc = rem - r * 20;
                int gr = r0 - 2 + r, gc = c0 - 2 + cc;
                float vv = 0.f;
                if ((unsigned)gr < 128u && (unsigned)gc < 128u)
                    vv = xin[ic * 16384 + gr * 128 + gc];
                in_bs[idx] = f2bf(vv);
            }
        }
        __syncthreads();

        // ---- conv1 MFMA: 21 groups of 16 positions over 4 waves ----
        for (int grp = wid; grp < 21; grp += 4) {
            int pos = grp * 16 + ocl;                 // A row
            int hy = pos / 18, hx = pos - hy * 18;
            int base = hy * 20 + hx;
            base = base > 357 ? 357 : base;           // clamp tail-group lanes
            bf16x8 afrag;
#pragma unroll
            for (int e = 0; e < 8; ++e)
                afrag[e] = (short)in_bs[base + offB[e]];
            f32x4 d0 = {0.f, 0.f, 0.f, 0.f}, d1 = {0.f, 0.f, 0.f, 0.f};
            d0 = __builtin_amdgcn_mfma_f32_16x16x32_bf16(afrag, c1b0, d0, 0, 0, 0);
            d1 = __builtin_amdgcn_mfma_f32_16x16x32_bf16(afrag, c1b1, d1, 0, 0, 0);
            int p0 = grp * 16 + g * 4;
            if (interior) {
#pragma unroll
                for (int r = 0; r < 4; ++r) {
                    int p2 = p0 + r;
                    if (p2 < 324) {
                        unsigned pk = pack_bf2(fmaxf(d0[r] + b1_e, 0.f),
                                               fmaxf(d1[r] + b1_o, 0.f));
                        *reinterpret_cast<unsigned*>(&h1_s[p2 * 40 + 2 * ocl]) = pk;
                    }
                }
            } else {
                int hy2 = p0 / 18, hx2 = p0 - hy2 * 18;
#pragma unroll
                for (int r = 0; r < 4; ++r) {
                    int p2 = p0 + r;
                    if (p2 < 324) {
                        bool valid = ((unsigned)(r0 - 1 + hy2) < 128u) &&
                                     ((unsigned)(c0 - 1 + hx2) < 128u);
                        float he = valid ? fmaxf(d0[r] + b1_e, 0.f) : 0.f;
                        float ho = valid ? fmaxf(d1[r] + b1_o, 0.f) : 0.f;
                        *reinterpret_cast<unsigned*>(&h1_s[p2 * 40 + 2 * ocl]) =
                            pack_bf2(he, ho);
                    }
                    ++hx2;
                    if (hx2 == 18) { hx2 = 0; ++hy2; }
                }
            }
        }
        __syncthreads();

        // ---- conv2: swapped operands (A=weights, B=h1) -> D[oc][x] ----
        const unsigned short* hb = &h1_s[((wid * 4) * 18 + ocl) * 40 + g * 8];
        f32x4 acc4[4];
#pragma unroll
        for (int q = 0; q < 4; ++q) acc4[q] = (f32x4){0.f, 0.f, 0.f, 0.f};
#pragma unroll
        for (int c = 0; c < 9; ++c) {
            const int ky = c / 3, kx = c - ky * 3;
#pragma unroll
            for (int q = 0; q < 4; ++q) {
                bf16x8 bfr = *reinterpret_cast<const bf16x8*>(
                    hb + ((q + ky) * 18 + kx) * 40);
                acc4[q] = __builtin_amdgcn_mfma_f32_16x16x32_bf16(
                    bfrag[c], bfr, acc4[q], 0, 0, 0);
            }
        }
        // conv3: lane holds P[oc=g*4+r][x=ocl]; 4 in-lane FMA + 2 shfl
#pragma unroll
        for (int q = 0; q < 4; ++q) {
            const int s = wid * 4 + q;
            float part3 = 0.f;
#pragma unroll
            for (int r = 0; r < 4; ++r)
                part3 = fmaf(fmaxf(acc4[q][r] + b2v[r], 0.f), w3v[r], part3);
            part3 += __shfl_xor(part3, 16);
            part3 += __shfl_xor(part3, 32);
            if (lane < 16) {
                int xw = lane;
                float msk = 1.f / (1.f + __expf(-(part3 + b3v)));
                out[776 + (size_t)img * 16384 + (size_t)(r0 + s) * 128 + (c0 + xw)] = msk;
                float f0  = bf2f(in_bs[      (s + 2) * 20 + (xw + 2)]);
                float f1v = bf2f(in_bs[400 + (s + 2) * 20 + (xw + 2)]);
                float f2v = bf2f(in_bs[800 + (s + 2) * 20 + (xw + 2)]);
                s0 = fmaf(msk, f0, s0);
                s1 = fmaf(msk, f1v, s1);
                s2 = fmaf(msk, f2v, s2);
                sm += msk;
            }
        }
    }

    // ---- block reduction of the 4 sums ----
#pragma unroll
    for (int off = 32; off > 0; off >>= 1) {
        s0 += __shfl_down(s0, off);
        s1 += __shfl_down(s1, off);
        s2 += __shfl_down(s2, off);
        sm += __shfl_down(sm, off);
    }
    if (lane == 0) { red[wid][0] = s0; red[wid][1] = s1; red[wid][2] = s2; red[wid][3] = sm; }
    __syncthreads();
    if (tid < 4) {
        float s = red[0][tid] + red[1][tid] + red[2][tid] + red[3][tid];
        colsum[(size_t)blockIdx.x * 4 + tid] = s;   // [img][part][4]
    }
}

// Tail: 1024 threads; ta2/ta3 vectorized (b128 + lane-shfl conv halo).
__global__ __launch_bounds__(1024) void tail_kernel(
    const float* __restrict__ colsum,
    const float* __restrict__ cw1, const float* __restrict__ cb1,
    const float* __restrict__ cw2, const float* __restrict__ cb2,
    const float* __restrict__ cw3, const float* __restrict__ cb3,
    const float* __restrict__ tw1, const float* __restrict__ tb1,
    const float* __restrict__ tw2, const float* __restrict__ tb2,
    const float* __restrict__ tw3, const float* __restrict__ tb3,
    const float* __restrict__ fw1, const float* __restrict__ fb1,
    const float* __restrict__ fw2, const float* __restrict__ fb2,
    const float* __restrict__ fw3, const float* __restrict__ fb3,
    float* __restrict__ out)
{
    const int b = blockIdx.x, tid = threadIdx.x;
    __shared__ float tmp[64][4];
    __shared__ float cs_s[3 * 64];
    __shared__ float e3s[3 * 64];
    __shared__ __align__(16) float f1[32 * 64];
    __shared__ __align__(16) float f2[64 * 64];
    __shared__ __align__(16) float tf[32 * 64];
    __shared__ float pooled[32], g1[64], g2[32], sca[8];

    if (tid < 256) {
        int t = tid >> 2, slot = tid & 3;
        const float* pp = colsum + (size_t)((b * 64 + t) * 16) * 4 + slot;
        float s = 0.f;
#pragma unroll
        for (int p = 0; p < 16; ++p) s += pp[p * 4];
        tmp[t][slot] = s;
    }
    __syncthreads();
    if (tid < 192) {
        int c = tid >> 6, t = tid & 63;
        float v = tmp[t][c] / (tmp[t][3] + 1e-8f);
        cs_s[tid] = v;
        out[8 + (b * 64 + t) * 3 + c] = v;
    }
    __syncthreads();

    if (tid < 64) {
        int t = tid;
        float c0v = cs_s[t], c1v = cs_s[64 + t], c2v = cs_s[128 + t];
        float e1[16];
#pragma unroll
        for (int o = 0; o < 16; ++o)
            e1[o] = fmaxf(cb1[o] + cw1[o * 3 + 0] * c0v + cw1[o * 3 + 1] * c1v
                                 + cw1[o * 3 + 2] * c2v, 0.f);
        float e2[8];
#pragma unroll
        for (int o = 0; o < 8; ++o) {
            float a = cb2[o];
#pragma unroll
            for (int i2 = 0; i2 < 16; ++i2) a += cw2[o * 16 + i2] * e1[i2];
            e2[o] = fmaxf(a, 0.f);
        }
#pragma unroll
        for (int o = 0; o < 3; ++o) {
            float a = cb3[o];
#pragma unroll
            for (int i2 = 0; i2 < 8; ++i2) a += cw3[o * 8 + i2] * e2[i2];
            e3s[o * 64 + t] = a;   // no relu on last ct conv
        }
    }
    __syncthreads();

    // ta1: 3->32 k3 p1
    {
        int o = tid >> 6, t = tid & 63;
#pragma unroll
        for (int h = 0; h < 2; ++h) {
            int oo = o + 16 * h;
            float a = tb1[oo];
#pragma unroll
            for (int ic = 0; ic < 3; ++ic)
#pragma unroll
                for (int k = 0; k < 3; ++k) {
                    int ttk = t + k - 1;
                    if ((unsigned)ttk < 64u)
                        a += e3s[ic * 64 + ttk] * tw1[(oo * 3 + ic) * 3 + k];
                }
            f1[oo * 64 + t] = fmaxf(a, 0.f);
        }
    }
    __syncthreads();

    // ta2: 32->64 k3 p1 — thread (oo=tid>>4, t4=tid&15) computes t=4t4..4t4+3
    {
        int oo = tid >> 4, t4 = tid & 15;
        float a0 = tb2[oo], a1 = a0, a2 = a0, a3 = a0;
        for (int ic = 0; ic < 32; ++ic) {
            f32x4 c = *reinterpret_cast<const f32x4*>(&f1[ic * 64 + t4 * 4]);
            float pm = __shfl_up(c[3], 1);
            float pp = __shfl_down(c[0], 1);
            if (t4 == 0)  pm = 0.f;          // t-1 < 0 pad
            if (t4 == 15) pp = 0.f;          // t+1 > 63 pad
            const float* wp = tw2 + (oo * 32 + ic) * 3;
            float w0 = wp[0], w1 = wp[1], w2 = wp[2];
            a0 = fmaf(w0, pm,   fmaf(w1, c[0], fmaf(w2, c[1], a0)));
            a1 = fmaf(w0, c[0], fmaf(w1, c[1], fmaf(w2, c[2], a1)));
            a2 = fmaf(w0, c[1], fmaf(w1, c[2], fmaf(w2, c[3], a2)));
            a3 = fmaf(w0, c[2], fmaf(w1, c[3], fmaf(w2, pp,   a3)));
        }
        f32x4 r = {fmaxf(a0, 0.f), fmaxf(a1, 0.f), fmaxf(a2, 0.f), fmaxf(a3, 0.f)};
        *reinterpret_cast<f32x4*>(&f2[oo * 64 + t4 * 4]) = r;
    }
    __syncthreads();

    // ta3: 64->32 k3 p1 (+ temporal_features out), threads 0..511
    if (tid < 512) {
        int oo = tid >> 4, t4 = tid & 15;
        float a0 = tb3[oo], a1 = a0, a2 = a0, a3 = a0;
        for (int ic = 0; ic < 64; ++ic) {
            f32x4 c = *reinterpret_cast<const f32x4*>(&f2[ic * 64 + t4 * 4]);
            float pm = __shfl_up(c[3], 1);
            float pp = __shfl_down(c[0], 1);
            if (t4 == 0)  pm = 0.f;
            if (t4 == 15) pp = 0.f;
            const float* wp = tw3 + (oo * 64 + ic) * 3;
            float w0 = wp[0], w1 = wp[1], w2 = wp[2];
            a0 = fmaf(w0, pm,   fmaf(w1, c[0], fmaf(w2, c[1], a0)));
            a1 = fmaf(w0, c[0], fmaf(w1, c[1], fmaf(w2, c[2], a1)));
            a2 = fmaf(w0, c[1], fmaf(w1, c[2], fmaf(w2, c[3], a2)));
            a3 = fmaf(w0, c[2], fmaf(w1, c[3], fmaf(w2, pp,   a3)));
        }
        f32x4 r = {fmaxf(a0, 0.f), fmaxf(a1, 0.f), fmaxf(a2, 0.f), fmaxf(a3, 0.f)};
        *reinterpret_cast<f32x4*>(&tf[oo * 64 + t4 * 4]) = r;
        *reinterpret_cast<f32x4*>(&out[TF_OFF + (b * 32 + oo) * 64 + t4 * 4]) = r;
    }
    __syncthreads();

    if (tid < 32) {
        float s = 0.f;
#pragma unroll
        for (int t4 = 0; t4 < 16; ++t4) {
            f32x4 c = *reinterpret_cast<const f32x4*>(&tf[tid * 64 + t4 * 4]);
            s += c[0] + c[1] + c[2] + c[3];
        }
        pooled[tid] = s * (1.f / 64.f);
    }
    __syncthreads();

    if (tid < 64) {
        float a = fb1[tid];
#pragma unroll
        for (int i2 = 0; i2 < 32; ++i2) a += pooled[i2] * fw1[tid * 32 + i2];
        g1[tid] = fmaxf(a, 0.f);
    }
    __syncthreads();
    if (tid < 32) {
        float a = fb2[tid];
        for (int i2 = 0; i2 < 64; ++i2) a += g1[i2] * fw2[tid * 64 + i2];
        g2[tid] = fmaxf(a, 0.f);
    }
    __syncthreads();
    if (tid == 0) {
        float a = fb3[0];
        for (int i2 = 0; i2 < 32; ++i2) a += g2[i2] * fw3[i2];
        float flow = 1.f / (1.f + expf(-a));
        sca[0] = flow;
        out[b] = flow;
    }
    if (tid >= 4 && tid < 7) {
        int c = tid - 4;
        float mu = 0.f;
        for (int t = 0; t < 64; ++t) mu += cs_s[c * 64 + t];
        mu *= (1.f / 64.f);
        float v = 0.f;
        for (int t = 0; t < 64; ++t) { float d = cs_s[c * 64 + t] - mu; v += d * d; }
        sca[1 + c] = sqrtf(v / 63.f);
    }
    __syncthreads();
    if (tid == 0) {
        float s0 = sca[1], s1 = sca[2], s2 = sca[3];
        float mu = (s0 + s1 + s2) * (1.f / 3.f);
        float var = ((s0 - mu) * (s0 - mu) + (s1 - mu) * (s1 - mu) + (s2 - mu) * (s2 - mu)) * 0.5f;
        float sy = 1.f / (1.f + expf(var));     // sigmoid(-var)
        out[4 + b] = sy;
        out[NAT_OFF + b] = (sca[0] + sy) * 0.5f;
    }
}

extern "C" void kernel_launch(void* const* d_in, const int* in_sizes, int n_in,
                              void* d_out, int out_size, void* d_ws, size_t ws_size,
                              hipStream_t stream)
{
    float* wsf = (float*)d_ws;
    float* out = (float*)d_out;

    seg_kernel<<<dim3(4096), 256, 0, stream>>>((const float*)d_in[0],
        (const float*)d_in[1], (const float*)d_in[2],
        (const float*)d_in[3], (const float*)d_in[4],
        (const float*)d_in[5], (const float*)d_in[6],
        wsf, out);

    tail_kernel<<<dim3(4), 1024, 0, stream>>>(wsf,
        (const float*)d_in[7],  (const float*)d_in[8],
        (const float*)d_in[9],  (const float*)d_in[10],
        (const float*)d_in[11], (const float*)d_in[12],
        (const float*)d_in[13], (const float*)d_in[14],
        (const float*)d_in[15], (const float*)d_in[16],
        (const float*)d_in[17], (const float*)d_in[18],
        (const float*)d_in[19], (const float*)d_in[20],
        (const float*)d_in[21], (const float*)d_in[22],
        (const float*)d_in[23], (const float*)d_in[24],
        out);
}

// Round 13
// 194.751 us; speedup vs baseline: 1.7088x; 1.0051x over previous
//
#include <hip/hip_runtime.h>
#include <hip/hip_bf16.h>

// BloodFlowSkinAnalyzer — f32 in/out (verified r5). Out layout (floats):
//   flow[4]@0, sync[4]@4, color[4*64*3]@8, masks[4,64,1,128,128]@776,
//   naturalness[4]@4195080, temporal[4,32,64]@4195084
// ws: colsum[4096][4] floats @0.
// Both seg convs on MFMA bf16 16x16x32 (operand layouts HW-verified r7/r8).
// r13: conv2 row-reuse — 18 ds_read_b128 per wave-tile instead of 36 (the
//      147KB/tile LDS re-read stream was the bottleneck; now 74KB). MFMA
//      accumulation order per q unchanged -> bit-identical output vs r12.

typedef __attribute__((ext_vector_type(8))) short bf16x8;
typedef __attribute__((ext_vector_type(4))) float f32x4;

#define NAT_OFF  4195080
#define TF_OFF   4195084

__device__ __forceinline__ unsigned short f2bf(float f) {   // RNE f32->bf16
    unsigned u = __float_as_uint(f);
    u += 0x7FFFu + ((u >> 16) & 1u);
    return (unsigned short)(u >> 16);
}
__device__ __forceinline__ float bf2f(unsigned short u) {
    return __uint_as_float((unsigned)u << 16);
}
__device__ __forceinline__ unsigned pack_bf2(float lo, float hi) {
    __hip_bfloat162 h2 = __float22bfloat162_rn(make_float2(lo, hi));
    return *reinterpret_cast<unsigned*>(&h2);   // .x in low 16 bits
}

// Fused seg: conv1(3->32,k3,p1) MFMA + conv2(32->16,k3,p1) MFMA +
// conv3(16->1,k1)+sigmoid + masked sums. Block = 4 of 64 16x16 tiles.
__global__ __launch_bounds__(256) void seg_kernel(
    const float* __restrict__ x,
    const float* __restrict__ w1f, const float* __restrict__ b1f,
    const float* __restrict__ w2f, const float* __restrict__ b2f,
    const float* __restrict__ w3f, const float* __restrict__ b3f,
    float* __restrict__ colsum, float* __restrict__ out)
{
    const int tid  = threadIdx.x;
    const int lane = tid & 63;
    const int wid  = tid >> 6;
    const int img  = blockIdx.x >> 4;        // b*64+t
    const int part = blockIdx.x & 15;        // 4 tiles per part

    __shared__ __align__(4)  unsigned short in_bs[1200];  // 3x20x20 bf16 halo
    __shared__ __align__(16) unsigned short h1_s[12960];  // [(y*18+x)*40+oc]
    __shared__ float red[4][4];

    const int ocl = lane & 15;   // free idx
    const int g   = lane >> 4;   // k-group (8 k's each)

    // ---- conv1 B-frags (k = ic*9+ky*3+kx, w1 native [oc][k]); k>=27 -> 0 ----
    bf16x8 c1b0, c1b1;
    int offB[8];                 // per-lane in_bs element offsets for A gather
#pragma unroll
    for (int e = 0; e < 8; ++e) {
        int k = g * 8 + e;
        if (k < 27) {
            int ic = k / 9, r2 = k - ic * 9, ky = r2 / 3, kx = r2 - ky * 3;
            offB[e] = ic * 400 + ky * 20 + kx;
            c1b0[e] = (short)f2bf(w1f[(2 * ocl)     * 27 + k]);
            c1b1[e] = (short)f2bf(w1f[(2 * ocl + 1) * 27 + k]);
        } else {
            offB[e] = 0;
            c1b0[e] = 0; c1b1[e] = 0;
        }
    }
    const float b1_e = b1f[2 * ocl], b1_o = b1f[2 * ocl + 1];

    // ---- conv2 W-frags (MFMA A operand after swap) ----
    bf16x8 bfrag[9];
#pragma unroll
    for (int c = 0; c < 9; ++c) {
        bf16x8 t;
#pragma unroll
        for (int e = 0; e < 8; ++e)
            t[e] = (short)f2bf(w2f[(ocl * 32 + g * 8 + e) * 9 + c]);
        bfrag[c] = t;
    }
    // conv3 per-lane constants for oc = g*4+r (D rows after swap)
    float b2v[4], w3v[4];
#pragma unroll
    for (int r = 0; r < 4; ++r) { b2v[r] = b2f[g * 4 + r]; w3v[r] = w3f[g * 4 + r]; }
    const float b3v = b3f[0];

    const float* xin = x + (size_t)img * 3 * 16384;
    float s0 = 0.f, s1 = 0.f, s2 = 0.f, sm = 0.f;

    for (int tt = 0; tt < 4; ++tt) {
        const int tile = part * 4 + tt;
        const int r0 = (tile >> 3) * 16, c0 = (tile & 7) * 16;
        const bool interior = (r0 >= 16 && r0 <= 96 && c0 >= 16 && c0 <= 96);
        __syncthreads();                     // prev-tile readers done

        // ---- stage 20x20x3 halo as bf16 ----
        if (interior) {                      // pair-packed: b64 load + b32 write
            const float* xb = xin + (r0 - 2) * 128 + (c0 - 2);
            for (int p = tid; p < 600; p += 256) {
                int ic = p / 200, rem = p - ic * 200;
                int r = rem / 10, cp = rem - r * 10;
                float2 v = *reinterpret_cast<const float2*>(
                    xb + ic * 16384 + r * 128 + cp * 2);
                *reinterpret_cast<unsigned*>(&in_bs[ic * 400 + r * 20 + cp * 2]) =
                    pack_bf2(v.x, v.y);
            }
        } else {
            for (int idx = tid; idx < 1200; idx += 256) {
                int ic = idx / 400, rem = idx - ic * 400;
                int r = rem / 20, cc = rem - r * 20;
                int gr = r0 - 2 + r, gc = c0 - 2 + cc;
                float vv = 0.f;
                if ((unsigned)gr < 128u && (unsigned)gc < 128u)
                    vv = xin[ic * 16384 + gr * 128 + gc];
                in_bs[idx] = f2bf(vv);
            }
        }
        __syncthreads();

        // ---- conv1 MFMA: 21 groups of 16 positions over 4 waves ----
        for (int grp = wid; grp < 21; grp += 4) {
            int pos = grp * 16 + ocl;                 // A row
            int hy = pos / 18, hx = pos - hy * 18;
            int base = hy * 20 + hx;
            base = base > 357 ? 357 : base;           // clamp tail-group lanes
            bf16x8 afrag;
#pragma unroll
            for (int e = 0; e < 8; ++e)
                afrag[e] = (short)in_bs[base + offB[e]];
            f32x4 d0 = {0.f, 0.f, 0.f, 0.f}, d1 = {0.f, 0.f, 0.f, 0.f};
            d0 = __builtin_amdgcn_mfma_f32_16x16x32_bf16(afrag, c1b0, d0, 0, 0, 0);
            d1 = __builtin_amdgcn_mfma_f32_16x16x32_bf16(afrag, c1b1, d1, 0, 0, 0);
            int p0 = grp * 16 + g * 4;
            if (interior) {
#pragma unroll
                for (int r = 0; r < 4; ++r) {
                    int p2 = p0 + r;
                    if (p2 < 324) {
                        unsigned pk = pack_bf2(fmaxf(d0[r] + b1_e, 0.f),
                                               fmaxf(d1[r] + b1_o, 0.f));
                        *reinterpret_cast<unsigned*>(&h1_s[p2 * 40 + 2 * ocl]) = pk;
                    }
                }
            } else {
                int hy2 = p0 / 18, hx2 = p0 - hy2 * 18;
#pragma unroll
                for (int r = 0; r < 4; ++r) {
                    int p2 = p0 + r;
                    if (p2 < 324) {
                        bool valid = ((unsigned)(r0 - 1 + hy2) < 128u) &&
                                     ((unsigned)(c0 - 1 + hx2) < 128u);
                        float he = valid ? fmaxf(d0[r] + b1_e, 0.f) : 0.f;
                        float ho = valid ? fmaxf(d1[r] + b1_o, 0.f) : 0.f;
                        *reinterpret_cast<unsigned*>(&h1_s[p2 * 40 + 2 * ocl]) =
                            pack_bf2(he, ho);
                    }
                    ++hx2;
                    if (hx2 == 18) { hx2 = 0; ++hy2; }
                }
            }
        }
        __syncthreads();

        // ---- conv2: swapped operands (A=weights, B=h1) -> D[oc][x].
        //      Row-reuse: rows r' = q+ky in 0..5; load each row's 3 kx
        //      fragments ONCE (18 b128 total, was 36), then issue all
        //      (q,ky) with q+ky==r'. Per-q accumulation order unchanged.
        const unsigned short* hb = &h1_s[((wid * 4) * 18 + ocl) * 40 + g * 8];
        f32x4 acc4[4];
#pragma unroll
        for (int q = 0; q < 4; ++q) acc4[q] = (f32x4){0.f, 0.f, 0.f, 0.f};
#pragma unroll
        for (int rp = 0; rp < 6; ++rp) {
            bf16x8 fr0 = *reinterpret_cast<const bf16x8*>(hb + (rp * 18 + 0) * 40);
            bf16x8 fr1 = *reinterpret_cast<const bf16x8*>(hb + (rp * 18 + 1) * 40);
            bf16x8 fr2 = *reinterpret_cast<const bf16x8*>(hb + (rp * 18 + 2) * 40);
#pragma unroll
            for (int ky = 0; ky < 3; ++ky) {
                const int q = rp - ky;
                if (q >= 0 && q < 4) {
                    acc4[q] = __builtin_amdgcn_mfma_f32_16x16x32_bf16(
                        bfrag[ky * 3 + 0], fr0, acc4[q], 0, 0, 0);
                    acc4[q] = __builtin_amdgcn_mfma_f32_16x16x32_bf16(
                        bfrag[ky * 3 + 1], fr1, acc4[q], 0, 0, 0);
                    acc4[q] = __builtin_amdgcn_mfma_f32_16x16x32_bf16(
                        bfrag[ky * 3 + 2], fr2, acc4[q], 0, 0, 0);
                }
            }
        }
        // conv3: lane holds P[oc=g*4+r][x=ocl]; 4 in-lane FMA + 2 shfl
#pragma unroll
        for (int q = 0; q < 4; ++q) {
            const int s = wid * 4 + q;
            float part3 = 0.f;
#pragma unroll
            for (int r = 0; r < 4; ++r)
                part3 = fmaf(fmaxf(acc4[q][r] + b2v[r], 0.f), w3v[r], part3);
            part3 += __shfl_xor(part3, 16);
            part3 += __shfl_xor(part3, 32);
            if (lane < 16) {
                int xw = lane;
                float msk = 1.f / (1.f + __expf(-(part3 + b3v)));
                out[776 + (size_t)img * 16384 + (size_t)(r0 + s) * 128 + (c0 + xw)] = msk;
                float f0  = bf2f(in_bs[      (s + 2) * 20 + (xw + 2)]);
                float f1v = bf2f(in_bs[400 + (s + 2) * 20 + (xw + 2)]);
                float f2v = bf2f(in_bs[800 + (s + 2) * 20 + (xw + 2)]);
                s0 = fmaf(msk, f0, s0);
                s1 = fmaf(msk, f1v, s1);
                s2 = fmaf(msk, f2v, s2);
                sm += msk;
            }
        }
    }

    // ---- block reduction of the 4 sums ----
#pragma unroll
    for (int off = 32; off > 0; off >>= 1) {
        s0 += __shfl_down(s0, off);
        s1 += __shfl_down(s1, off);
        s2 += __shfl_down(s2, off);
        sm += __shfl_down(sm, off);
    }
    if (lane == 0) { red[wid][0] = s0; red[wid][1] = s1; red[wid][2] = s2; red[wid][3] = sm; }
    __syncthreads();
    if (tid < 4) {
        float s = red[0][tid] + red[1][tid] + red[2][tid] + red[3][tid];
        colsum[(size_t)blockIdx.x * 4 + tid] = s;   // [img][part][4]
    }
}

// Tail: 1024 threads; ta2/ta3 vectorized (b128 + lane-shfl conv halo).
__global__ __launch_bounds__(1024) void tail_kernel(
    const float* __restrict__ colsum,
    const float* __restrict__ cw1, const float* __restrict__ cb1,
    const float* __restrict__ cw2, const float* __restrict__ cb2,
    const float* __restrict__ cw3, const float* __restrict__ cb3,
    const float* __restrict__ tw1, const float* __restrict__ tb1,
    const float* __restrict__ tw2, const float* __restrict__ tb2,
    const float* __restrict__ tw3, const float* __restrict__ tb3,
    const float* __restrict__ fw1, const float* __restrict__ fb1,
    const float* __restrict__ fw2, const float* __restrict__ fb2,
    const float* __restrict__ fw3, const float* __restrict__ fb3,
    float* __restrict__ out)
{
    const int b = blockIdx.x, tid = threadIdx.x;
    __shared__ float tmp[64][4];
    __shared__ float cs_s[3 * 64];
    __shared__ float e3s[3 * 64];
    __shared__ __align__(16) float f1[32 * 64];
    __shared__ __align__(16) float f2[64 * 64];
    __shared__ __align__(16) float tf[32 * 64];
    __shared__ float pooled[32], g1[64], g2[32], sca[8];

    if (tid < 256) {
        int t = tid >> 2, slot = tid & 3;
        const float* pp = colsum + (size_t)((b * 64 + t) * 16) * 4 + slot;
        float s = 0.f;
#pragma unroll
        for (int p = 0; p < 16; ++p) s += pp[p * 4];
        tmp[t][slot] = s;
    }
    __syncthreads();
    if (tid < 192) {
        int c = tid >> 6, t = tid & 63;
        float v = tmp[t][c] / (tmp[t][3] + 1e-8f);
        cs_s[tid] = v;
        out[8 + (b * 64 + t) * 3 + c] = v;
    }
    __syncthreads();

    if (tid < 64) {
        int t = tid;
        float c0v = cs_s[t], c1v = cs_s[64 + t], c2v = cs_s[128 + t];
        float e1[16];
#pragma unroll
        for (int o = 0; o < 16; ++o)
            e1[o] = fmaxf(cb1[o] + cw1[o * 3 + 0] * c0v + cw1[o * 3 + 1] * c1v
                                 + cw1[o * 3 + 2] * c2v, 0.f);
        float e2[8];
#pragma unroll
        for (int o = 0; o < 8; ++o) {
            float a = cb2[o];
#pragma unroll
            for (int i2 = 0; i2 < 16; ++i2) a += cw2[o * 16 + i2] * e1[i2];
            e2[o] = fmaxf(a, 0.f);
        }
#pragma unroll
        for (int o = 0; o < 3; ++o) {
            float a = cb3[o];
#pragma unroll
            for (int i2 = 0; i2 < 8; ++i2) a += cw3[o * 8 + i2] * e2[i2];
            e3s[o * 64 + t] = a;   // no relu on last ct conv
        }
    }
    __syncthreads();

    // ta1: 3->32 k3 p1
    {
        int o = tid >> 6, t = tid & 63;
#pragma unroll
        for (int h = 0; h < 2; ++h) {
            int oo = o + 16 * h;
            float a = tb1[oo];
#pragma unroll
            for (int ic = 0; ic < 3; ++ic)
#pragma unroll
                for (int k = 0; k < 3; ++k) {
                    int ttk = t + k - 1;
                    if ((unsigned)ttk < 64u)
                        a += e3s[ic * 64 + ttk] * tw1[(oo * 3 + ic) * 3 + k];
                }
            f1[oo * 64 + t] = fmaxf(a, 0.f);
        }
    }
    __syncthreads();

    // ta2: 32->64 k3 p1 — thread (oo=tid>>4, t4=tid&15) computes t=4t4..4t4+3
    {
        int oo = tid >> 4, t4 = tid & 15;
        float a0 = tb2[oo], a1 = a0, a2 = a0, a3 = a0;
        for (int ic = 0; ic < 32; ++ic) {
            f32x4 c = *reinterpret_cast<const f32x4*>(&f1[ic * 64 + t4 * 4]);
            float pm = __shfl_up(c[3], 1);
            float pp = __shfl_down(c[0], 1);
            if (t4 == 0)  pm = 0.f;          // t-1 < 0 pad
            if (t4 == 15) pp = 0.f;          // t+1 > 63 pad
            const float* wp = tw2 + (oo * 32 + ic) * 3;
            float w0 = wp[0], w1 = wp[1], w2 = wp[2];
            a0 = fmaf(w0, pm,   fmaf(w1, c[0], fmaf(w2, c[1], a0)));
            a1 = fmaf(w0, c[0], fmaf(w1, c[1], fmaf(w2, c[2], a1)));
            a2 = fmaf(w0, c[1], fmaf(w1, c[2], fmaf(w2, c[3], a2)));
            a3 = fmaf(w0, c[2], fmaf(w1, c[3], fmaf(w2, pp,   a3)));
        }
        f32x4 r = {fmaxf(a0, 0.f), fmaxf(a1, 0.f), fmaxf(a2, 0.f), fmaxf(a3, 0.f)};
        *reinterpret_cast<f32x4*>(&f2[oo * 64 + t4 * 4]) = r;
    }
    __syncthreads();

    // ta3: 64->32 k3 p1 (+ temporal_features out), threads 0..511
    if (tid < 512) {
        int oo = tid >> 4, t4 = tid & 15;
        float a0 = tb3[oo], a1 = a0, a2 = a0, a3 = a0;
        for (int ic = 0; ic < 64; ++ic) {
            f32x4 c = *reinterpret_cast<const f32x4*>(&f2[ic * 64 + t4 * 4]);
            float pm = __shfl_up(c[3], 1);
            float pp = __shfl_down(c[0], 1);
            if (t4 == 0)  pm = 0.f;
            if (t4 == 15) pp = 0.f;
            const float* wp = tw3 + (oo * 64 + ic) * 3;
            float w0 = wp[0], w1 = wp[1], w2 = wp[2];
            a0 = fmaf(w0, pm,   fmaf(w1, c[0], fmaf(w2, c[1], a0)));
            a1 = fmaf(w0, c[0], fmaf(w1, c[1], fmaf(w2, c[2], a1)));
            a2 = fmaf(w0, c[1], fmaf(w1, c[2], fmaf(w2, c[3], a2)));
            a3 = fmaf(w0, c[2], fmaf(w1, c[3], fmaf(w2, pp,   a3)));
        }
        f32x4 r = {fmaxf(a0, 0.f), fmaxf(a1, 0.f), fmaxf(a2, 0.f), fmaxf(a3, 0.f)};
        *reinterpret_cast<f32x4*>(&tf[oo * 64 + t4 * 4]) = r;
        *reinterpret_cast<f32x4*>(&out[TF_OFF + (b * 32 + oo) * 64 + t4 * 4]) = r;
    }
    __syncthreads();

    if (tid < 32) {
        float s = 0.f;
#pragma unroll
        for (int t4 = 0; t4 < 16; ++t4) {
            f32x4 c = *reinterpret_cast<const f32x4*>(&tf[tid * 64 + t4 * 4]);
            s += c[0] + c[1] + c[2] + c[3];
        }
        pooled[tid] = s * (1.f / 64.f);
    }
    __syncthreads();

    if (tid < 64) {
        float a = fb1[tid];
#pragma unroll
        for (int i2 = 0; i2 < 32; ++i2) a += pooled[i2] * fw1[tid * 32 + i2];
        g1[tid] = fmaxf(a, 0.f);
    }
    __syncthreads();
    if (tid < 32) {
        float a = fb2[tid];
        for (int i2 = 0; i2 < 64; ++i2) a += g1[i2] * fw2[tid * 64 + i2];
        g2[tid] = fmaxf(a, 0.f);
    }
    __syncthreads();
    if (tid == 0) {
        float a = fb3[0];
        for (int i2 = 0; i2 < 32; ++i2) a += g2[i2] * fw3[i2];
        float flow = 1.f / (1.f + expf(-a));
        sca[0] = flow;
        out[b] = flow;
    }
    if (tid >= 4 && tid < 7) {
        int c = tid - 4;
        float mu = 0.f;
        for (int t = 0; t < 64; ++t) mu += cs_s[c * 64 + t];
        mu *= (1.f / 64.f);
        float v = 0.f;
        for (int t = 0; t < 64; ++t) { float d = cs_s[c * 64 + t] - mu; v += d * d; }
        sca[1 + c] = sqrtf(v / 63.f);
    }
    __syncthreads();
    if (tid == 0) {
        float s0 = sca[1], s1 = sca[2], s2 = sca[3];
        float mu = (s0 + s1 + s2) * (1.f / 3.f);
        float var = ((s0 - mu) * (s0 - mu) + (s1 - mu) * (s1 - mu) + (s2 - mu) * (s2 - mu)) * 0.5f;
        float sy = 1.f / (1.f + expf(var));     // sigmoid(-var)
        out[4 + b] = sy;
        out[NAT_OFF + b] = (sca[0] + sy) * 0.5f;
    }
}

extern "C" void kernel_launch(void* const* d_in, const int* in_sizes, int n_in,
                              void* d_out, int out_size, void* d_ws, size_t ws_size,
                              hipStream_t stream)
{
    float* wsf = (float*)d_ws;
    float* out = (float*)d_out;

    seg_kernel<<<dim3(4096), 256, 0, stream>>>((const float*)d_in[0],
        (const float*)d_in[1], (const float*)d_in[2],
        (const float*)d_in[3], (const float*)d_in[4],
        (const float*)d_in[5], (const float*)d_in[6],
        wsf, out);

    tail_kernel<<<dim3(4), 1024, 0, stream>>>(wsf,
        (const float*)d_in[7],  (const float*)d_in[8],
        (const float*)d_in[9],  (const float*)d_in[10],
        (const float*)d_in[11], (const float*)d_in[12],
        (const float*)d_in[13], (const float*)d_in[14],
        (const float*)d_in[15], (const float*)d_in[16],
        (const float*)d_in[17], (const float*)d_in[18],
        (const float*)d_in[19], (const float*)d_in[20],
        (const float*)d_in[21], (const float*)d_in[22],
        (const float*)d_in[23], (const float*)d_in[24],
        out);
}

// Round 14
// 174.351 us; speedup vs baseline: 1.9087x; 1.1170x over previous
//
#include <hip/hip_runtime.h>
#include <hip/hip_bf16.h>

// BloodFlowSkinAnalyzer — f32 in/out (verified r5). Out layout (floats):
//   flow[4]@0, sync[4]@4, color[4*64*3]@8, masks[4,64,1,128,128]@776,
//   naturalness[4]@4195080, temporal[4,32,64]@4195084
// ws: colsum[4096][4] floats @0.
// Both seg convs on MFMA bf16 16x16x32 (operand layouts HW-verified r7/r8).
// r14: r13 + minimal-register tile pipelining — in_bs double-buffered, next
//      tile's 5 loads issued before conv1 (values only in VGPRs, addresses
//      recomputed -> no r10 VGPR bloat), ds_write after conv2, 2 barriers/tile.

typedef __attribute__((ext_vector_type(8))) short bf16x8;
typedef __attribute__((ext_vector_type(4))) float f32x4;

#define NAT_OFF  4195080
#define TF_OFF   4195084

__device__ __forceinline__ unsigned short f2bf(float f) {   // RNE f32->bf16
    unsigned u = __float_as_uint(f);
    u += 0x7FFFu + ((u >> 16) & 1u);
    return (unsigned short)(u >> 16);
}
__device__ __forceinline__ float bf2f(unsigned short u) {
    return __uint_as_float((unsigned)u << 16);
}
__device__ __forceinline__ unsigned pack_bf2(float lo, float hi) {
    __hip_bfloat162 h2 = __float22bfloat162_rn(make_float2(lo, hi));
    return *reinterpret_cast<unsigned*>(&h2);   // .x in low 16 bits
}

// Fused seg: conv1(3->32,k3,p1) MFMA + conv2(32->16,k3,p1) MFMA +
// conv3(16->1,k1)+sigmoid + masked sums. Block = 4 of 64 16x16 tiles.
__global__ __launch_bounds__(256) void seg_kernel(
    const float* __restrict__ x,
    const float* __restrict__ w1f, const float* __restrict__ b1f,
    const float* __restrict__ w2f, const float* __restrict__ b2f,
    const float* __restrict__ w3f, const float* __restrict__ b3f,
    float* __restrict__ colsum, float* __restrict__ out)
{
    const int tid  = threadIdx.x;
    const int lane = tid & 63;
    const int wid  = tid >> 6;
    const int img  = blockIdx.x >> 4;        // b*64+t
    const int part = blockIdx.x & 15;        // 4 tiles per part

    __shared__ __align__(4)  unsigned short in_bs[2][1200]; // dbuf 3x20x20 bf16
    __shared__ __align__(16) unsigned short h1_s[12960];    // [(y*18+x)*40+oc]
    __shared__ float red[4][4];

    const int ocl = lane & 15;   // free idx
    const int g   = lane >> 4;   // k-group (8 k's each)

    // ---- conv1 B-frags (k = ic*9+ky*3+kx, w1 native [oc][k]); k>=27 -> 0 ----
    bf16x8 c1b0, c1b1;
    int offB[8];                 // per-lane in_bs element offsets for A gather
#pragma unroll
    for (int e = 0; e < 8; ++e) {
        int k = g * 8 + e;
        if (k < 27) {
            int ic = k / 9, r2 = k - ic * 9, ky = r2 / 3, kx = r2 - ky * 3;
            offB[e] = ic * 400 + ky * 20 + kx;
            c1b0[e] = (short)f2bf(w1f[(2 * ocl)     * 27 + k]);
            c1b1[e] = (short)f2bf(w1f[(2 * ocl + 1) * 27 + k]);
        } else {
            offB[e] = 0;
            c1b0[e] = 0; c1b1[e] = 0;
        }
    }
    const float b1_e = b1f[2 * ocl], b1_o = b1f[2 * ocl + 1];

    // ---- conv2 W-frags (MFMA A operand after swap) ----
    bf16x8 bfrag[9];
#pragma unroll
    for (int c = 0; c < 9; ++c) {
        bf16x8 t;
#pragma unroll
        for (int e = 0; e < 8; ++e)
            t[e] = (short)f2bf(w2f[(ocl * 32 + g * 8 + e) * 9 + c]);
        bfrag[c] = t;
    }
    // conv3 per-lane constants for oc = g*4+r (D rows after swap)
    float b2v[4], w3v[4];
#pragma unroll
    for (int r = 0; r < 4; ++r) { b2v[r] = b2f[g * 4 + r]; w3v[r] = w3f[g * 4 + r]; }
    const float b3v = b3f[0];

    const float* xin = x + (size_t)img * 3 * 16384;
    float s0 = 0.f, s1 = 0.f, s2 = 0.f, sm = 0.f;

    // ---- prologue: stage tile 0 into buffer 0 ----
    {
        const int tile0 = part * 4;
        const int r0 = (tile0 >> 3) * 16, c0 = (tile0 & 7) * 16;
        for (int idx = tid; idx < 1200; idx += 256) {
            int ic = idx / 400, rem = idx - ic * 400;
            int r = rem / 20, cc = rem - r * 20;
            int gr = r0 - 2 + r, gc = c0 - 2 + cc;
            float vv = 0.f;
            if ((unsigned)gr < 128u && (unsigned)gc < 128u)
                vv = xin[ic * 16384 + gr * 128 + gc];
            in_bs[0][idx] = f2bf(vv);
        }
    }
    __syncthreads();

    for (int tt = 0; tt < 4; ++tt) {
        const int cur = tt & 1;
        const unsigned short* inb = in_bs[cur];
        const int tile = part * 4 + tt;
        const int r0 = (tile >> 3) * 16, c0 = (tile & 7) * 16;
        const bool interior = (r0 >= 16 && r0 <= 96 && c0 >= 16 && c0 <= 96);

        // ---- issue next tile's loads NOW (latency hides under conv1+conv2).
        //      Values only in VGPRs; addresses recomputed (no r10 bloat).
        float nv[5];
        if (tt < 3) {
            const int tn = tile + 1;
            const int r0n = (tn >> 3) * 16, c0n = (tn & 7) * 16;
#pragma unroll
            for (int s = 0; s < 5; ++s) {
                int idx = tid + 256 * s;
                nv[s] = 0.f;
                if (idx < 1200) {
                    int ic = idx / 400, rem = idx - ic * 400;
                    int r = rem / 20, cc = rem - r * 20;
                    int gr = r0n - 2 + r, gc = c0n - 2 + cc;
                    if ((unsigned)gr < 128u && (unsigned)gc < 128u)
                        nv[s] = xin[ic * 16384 + gr * 128 + gc];
                }
            }
        }

        // ---- conv1 MFMA: 21 groups of 16 positions over 4 waves ----
        for (int grp = wid; grp < 21; grp += 4) {
            int pos = grp * 16 + ocl;                 // A row
            int hy = pos / 18, hx = pos - hy * 18;
            int base = hy * 20 + hx;
            base = base > 357 ? 357 : base;           // clamp tail-group lanes
            bf16x8 afrag;
#pragma unroll
            for (int e = 0; e < 8; ++e)
                afrag[e] = (short)inb[base + offB[e]];
            f32x4 d0 = {0.f, 0.f, 0.f, 0.f}, d1 = {0.f, 0.f, 0.f, 0.f};
            d0 = __builtin_amdgcn_mfma_f32_16x16x32_bf16(afrag, c1b0, d0, 0, 0, 0);
            d1 = __builtin_amdgcn_mfma_f32_16x16x32_bf16(afrag, c1b1, d1, 0, 0, 0);
            int p0 = grp * 16 + g * 4;
            if (interior) {
#pragma unroll
                for (int r = 0; r < 4; ++r) {
                    int p2 = p0 + r;
                    if (p2 < 324) {
                        unsigned pk = pack_bf2(fmaxf(d0[r] + b1_e, 0.f),
                                               fmaxf(d1[r] + b1_o, 0.f));
                        *reinterpret_cast<unsigned*>(&h1_s[p2 * 40 + 2 * ocl]) = pk;
                    }
                }
            } else {
                int hy2 = p0 / 18, hx2 = p0 - hy2 * 18;
#pragma unroll
                for (int r = 0; r < 4; ++r) {
                    int p2 = p0 + r;
                    if (p2 < 324) {
                        bool valid = ((unsigned)(r0 - 1 + hy2) < 128u) &&
                                     ((unsigned)(c0 - 1 + hx2) < 128u);
                        float he = valid ? fmaxf(d0[r] + b1_e, 0.f) : 0.f;
                        float ho = valid ? fmaxf(d1[r] + b1_o, 0.f) : 0.f;
                        *reinterpret_cast<unsigned*>(&h1_s[p2 * 40 + 2 * ocl]) =
                            pack_bf2(he, ho);
                    }
                    ++hx2;
                    if (hx2 == 18) { hx2 = 0; ++hy2; }
                }
            }
        }
        __syncthreads();

        // ---- conv2: swapped operands (A=weights, B=h1) -> D[oc][x].
        //      Row-reuse: 18 b128 reads; per-q accumulation order fixed.
        const unsigned short* hb = &h1_s[((wid * 4) * 18 + ocl) * 40 + g * 8];
        f32x4 acc4[4];
#pragma unroll
        for (int q = 0; q < 4; ++q) acc4[q] = (f32x4){0.f, 0.f, 0.f, 0.f};
#pragma unroll
        for (int rp = 0; rp < 6; ++rp) {
            bf16x8 fr0 = *reinterpret_cast<const bf16x8*>(hb + (rp * 18 + 0) * 40);
            bf16x8 fr1 = *reinterpret_cast<const bf16x8*>(hb + (rp * 18 + 1) * 40);
            bf16x8 fr2 = *reinterpret_cast<const bf16x8*>(hb + (rp * 18 + 2) * 40);
#pragma unroll
            for (int ky = 0; ky < 3; ++ky) {
                const int q = rp - ky;
                if (q >= 0 && q < 4) {
                    acc4[q] = __builtin_amdgcn_mfma_f32_16x16x32_bf16(
                        bfrag[ky * 3 + 0], fr0, acc4[q], 0, 0, 0);
                    acc4[q] = __builtin_amdgcn_mfma_f32_16x16x32_bf16(
                        bfrag[ky * 3 + 1], fr1, acc4[q], 0, 0, 0);
                    acc4[q] = __builtin_amdgcn_mfma_f32_16x16x32_bf16(
                        bfrag[ky * 3 + 2], fr2, acc4[q], 0, 0, 0);
                }
            }
        }
        // conv3: lane holds P[oc=g*4+r][x=ocl]; 4 in-lane FMA + 2 shfl
#pragma unroll
        for (int q = 0; q < 4; ++q) {
            const int s = wid * 4 + q;
            float part3 = 0.f;
#pragma unroll
            for (int r = 0; r < 4; ++r)
                part3 = fmaf(fmaxf(acc4[q][r] + b2v[r], 0.f), w3v[r], part3);
            part3 += __shfl_xor(part3, 16);
            part3 += __shfl_xor(part3, 32);
            if (lane < 16) {
                int xw = lane;
                float msk = 1.f / (1.f + __expf(-(part3 + b3v)));
                out[776 + (size_t)img * 16384 + (size_t)(r0 + s) * 128 + (c0 + xw)] = msk;
                float f0  = bf2f(inb[      (s + 2) * 20 + (xw + 2)]);
                float f1v = bf2f(inb[400 + (s + 2) * 20 + (xw + 2)]);
                float f2v = bf2f(inb[800 + (s + 2) * 20 + (xw + 2)]);
                s0 = fmaf(msk, f0, s0);
                s1 = fmaf(msk, f1v, s1);
                s2 = fmaf(msk, f2v, s2);
                sm += msk;
            }
        }

        // ---- write next tile's halo into the other buffer ----
        if (tt < 3) {
#pragma unroll
            for (int s = 0; s < 5; ++s) {
                int idx = tid + 256 * s;
                if (idx < 1200) in_bs[cur ^ 1][idx] = f2bf(nv[s]);
            }
        }
        __syncthreads();
    }

    // ---- block reduction of the 4 sums ----
#pragma unroll
    for (int off = 32; off > 0; off >>= 1) {
        s0 += __shfl_down(s0, off);
        s1 += __shfl_down(s1, off);
        s2 += __shfl_down(s2, off);
        sm += __shfl_down(sm, off);
    }
    if (lane == 0) { red[wid][0] = s0; red[wid][1] = s1; red[wid][2] = s2; red[wid][3] = sm; }
    __syncthreads();
    if (tid < 4) {
        float s = red[0][tid] + red[1][tid] + red[2][tid] + red[3][tid];
        colsum[(size_t)blockIdx.x * 4 + tid] = s;   // [img][part][4]
    }
}

// Tail: 1024 threads; ta2/ta3 vectorized (b128 + lane-shfl conv halo).
__global__ __launch_bounds__(1024) void tail_kernel(
    const float* __restrict__ colsum,
    const float* __restrict__ cw1, const float* __restrict__ cb1,
    const float* __restrict__ cw2, const float* __restrict__ cb2,
    const float* __restrict__ cw3, const float* __restrict__ cb3,
    const float* __restrict__ tw1, const float* __restrict__ tb1,
    const float* __restrict__ tw2, const float* __restrict__ tb2,
    const float* __restrict__ tw3, const float* __restrict__ tb3,
    const float* __restrict__ fw1, const float* __restrict__ fb1,
    const float* __restrict__ fw2, const float* __restrict__ fb2,
    const float* __restrict__ fw3, const float* __restrict__ fb3,
    float* __restrict__ out)
{
    const int b = blockIdx.x, tid = threadIdx.x;
    __shared__ float tmp[64][4];
    __shared__ float cs_s[3 * 64];
    __shared__ float e3s[3 * 64];
    __shared__ __align__(16) float f1[32 * 64];
    __shared__ __align__(16) float f2[64 * 64];
    __shared__ __align__(16) float tf[32 * 64];
    __shared__ float pooled[32], g1[64], g2[32], sca[8];

    if (tid < 256) {
        int t = tid >> 2, slot = tid & 3;
        const float* pp = colsum + (size_t)((b * 64 + t) * 16) * 4 + slot;
        float s = 0.f;
#pragma unroll
        for (int p = 0; p < 16; ++p) s += pp[p * 4];
        tmp[t][slot] = s;
    }
    __syncthreads();
    if (tid < 192) {
        int c = tid >> 6, t = tid & 63;
        float v = tmp[t][c] / (tmp[t][3] + 1e-8f);
        cs_s[tid] = v;
        out[8 + (b * 64 + t) * 3 + c] = v;
    }
    __syncthreads();

    if (tid < 64) {
        int t = tid;
        float c0v = cs_s[t], c1v = cs_s[64 + t], c2v = cs_s[128 + t];
        float e1[16];
#pragma unroll
        for (int o = 0; o < 16; ++o)
            e1[o] = fmaxf(cb1[o] + cw1[o * 3 + 0] * c0v + cw1[o * 3 + 1] * c1v
                                 + cw1[o * 3 + 2] * c2v, 0.f);
        float e2[8];
#pragma unroll
        for (int o = 0; o < 8; ++o) {
            float a = cb2[o];
#pragma unroll
            for (int i2 = 0; i2 < 16; ++i2) a += cw2[o * 16 + i2] * e1[i2];
            e2[o] = fmaxf(a, 0.f);
        }
#pragma unroll
        for (int o = 0; o < 3; ++o) {
            float a = cb3[o];
#pragma unroll
            for (int i2 = 0; i2 < 8; ++i2) a += cw3[o * 8 + i2] * e2[i2];
            e3s[o * 64 + t] = a;   // no relu on last ct conv
        }
    }
    __syncthreads();

    // ta1: 3->32 k3 p1
    {
        int o = tid >> 6, t = tid & 63;
#pragma unroll
        for (int h = 0; h < 2; ++h) {
            int oo = o + 16 * h;
            float a = tb1[oo];
#pragma unroll
            for (int ic = 0; ic < 3; ++ic)
#pragma unroll
                for (int k = 0; k < 3; ++k) {
                    int ttk = t + k - 1;
                    if ((unsigned)ttk < 64u)
                        a += e3s[ic * 64 + ttk] * tw1[(oo * 3 + ic) * 3 + k];
                }
            f1[oo * 64 + t] = fmaxf(a, 0.f);
        }
    }
    __syncthreads();

    // ta2: 32->64 k3 p1 — thread (oo=tid>>4, t4=tid&15) computes t=4t4..4t4+3
    {
        int oo = tid >> 4, t4 = tid & 15;
        float a0 = tb2[oo], a1 = a0, a2 = a0, a3 = a0;
        for (int ic = 0; ic < 32; ++ic) {
            f32x4 c = *reinterpret_cast<const f32x4*>(&f1[ic * 64 + t4 * 4]);
            float pm = __shfl_up(c[3], 1);
            float pp = __shfl_down(c[0], 1);
            if (t4 == 0)  pm = 0.f;          // t-1 < 0 pad
            if (t4 == 15) pp = 0.f;          // t+1 > 63 pad
            const float* wp = tw2 + (oo * 32 + ic) * 3;
            float w0 = wp[0], w1 = wp[1], w2 = wp[2];
            a0 = fmaf(w0, pm,   fmaf(w1, c[0], fmaf(w2, c[1], a0)));
            a1 = fmaf(w0, c[0], fmaf(w1, c[1], fmaf(w2, c[2], a1)));
            a2 = fmaf(w0, c[1], fmaf(w1, c[2], fmaf(w2, c[3], a2)));
            a3 = fmaf(w0, c[2], fmaf(w1, c[3], fmaf(w2, pp,   a3)));
        }
        f32x4 r = {fmaxf(a0, 0.f), fmaxf(a1, 0.f), fmaxf(a2, 0.f), fmaxf(a3, 0.f)};
        *reinterpret_cast<f32x4*>(&f2[oo * 64 + t4 * 4]) = r;
    }
    __syncthreads();

    // ta3: 64->32 k3 p1 (+ temporal_features out), threads 0..511
    if (tid < 512) {
        int oo = tid >> 4, t4 = tid & 15;
        float a0 = tb3[oo], a1 = a0, a2 = a0, a3 = a0;
        for (int ic = 0; ic < 64; ++ic) {
            f32x4 c = *reinterpret_cast<const f32x4*>(&f2[ic * 64 + t4 * 4]);
            float pm = __shfl_up(c[3], 1);
            float pp = __shfl_down(c[0], 1);
            if (t4 == 0)  pm = 0.f;
            if (t4 == 15) pp = 0.f;
            const float* wp = tw3 + (oo * 64 + ic) * 3;
            float w0 = wp[0], w1 = wp[1], w2 = wp[2];
            a0 = fmaf(w0, pm,   fmaf(w1, c[0], fmaf(w2, c[1], a0)));
            a1 = fmaf(w0, c[0], fmaf(w1, c[1], fmaf(w2, c[2], a1)));
            a2 = fmaf(w0, c[1], fmaf(w1, c[2], fmaf(w2, c[3], a2)));
            a3 = fmaf(w0, c[2], fmaf(w1, c[3], fmaf(w2, pp,   a3)));
        }
        f32x4 r = {fmaxf(a0, 0.f), fmaxf(a1, 0.f), fmaxf(a2, 0.f), fmaxf(a3, 0.f)};
        *reinterpret_cast<f32x4*>(&tf[oo * 64 + t4 * 4]) = r;
        *reinterpret_cast<f32x4*>(&out[TF_OFF + (b * 32 + oo) * 64 + t4 * 4]) = r;
    }
    __syncthreads();

    if (tid < 32) {
        float s = 0.f;
#pragma unroll
        for (int t4 = 0; t4 < 16; ++t4) {
            f32x4 c = *reinterpret_cast<const f32x4*>(&tf[tid * 64 + t4 * 4]);
            s += c[0] + c[1] + c[2] + c[3];
        }
        pooled[tid] = s * (1.f / 64.f);
    }
    __syncthreads();

    if (tid < 64) {
        float a = fb1[tid];
#pragma unroll
        for (int i2 = 0; i2 < 32; ++i2) a += pooled[i2] * fw1[tid * 32 + i2];
        g1[tid] = fmaxf(a, 0.f);
    }
    __syncthreads();
    if (tid < 32) {
        float a = fb2[tid];
        for (int i2 = 0; i2 < 64; ++i2) a += g1[i2] * fw2[tid * 64 + i2];
        g2[tid] = fmaxf(a, 0.f);
    }
    __syncthreads();
    if (tid == 0) {
        float a = fb3[0];
        for (int i2 = 0; i2 < 32; ++i2) a += g2[i2] * fw3[i2];
        float flow = 1.f / (1.f + expf(-a));
        sca[0] = flow;
        out[b] = flow;
    }
    if (tid >= 4 && tid < 7) {
        int c = tid - 4;
        float mu = 0.f;
        for (int t = 0; t < 64; ++t) mu += cs_s[c * 64 + t];
        mu *= (1.f / 64.f);
        float v = 0.f;
        for (int t = 0; t < 64; ++t) { float d = cs_s[c * 64 + t] - mu; v += d * d; }
        sca[1 + c] = sqrtf(v / 63.f);
    }
    __syncthreads();
    if (tid == 0) {
        float s0 = sca[1], s1 = sca[2], s2 = sca[3];
        float mu = (s0 + s1 + s2) * (1.f / 3.f);
        float var = ((s0 - mu) * (s0 - mu) + (s1 - mu) * (s1 - mu) + (s2 - mu) * (s2 - mu)) * 0.5f;
        float sy = 1.f / (1.f + expf(var));     // sigmoid(-var)
        out[4 + b] = sy;
        out[NAT_OFF + b] = (sca[0] + sy) * 0.5f;
    }
}

extern "C" void kernel_launch(void* const* d_in, const int* in_sizes, int n_in,
                              void* d_out, int out_size, void* d_ws, size_t ws_size,
                              hipStream_t stream)
{
    float* wsf = (float*)d_ws;
    float* out = (float*)d_out;

    seg_kernel<<<dim3(4096), 256, 0, stream>>>((const float*)d_in[0],
        (const float*)d_in[1], (const float*)d_in[2],
        (const float*)d_in[3], (const float*)d_in[4],
        (const float*)d_in[5], (const float*)d_in[6],
        wsf, out);

    tail_kernel<<<dim3(4), 1024, 0, stream>>>(wsf,
        (const float*)d_in[7],  (const float*)d_in[8],
        (const float*)d_in[9],  (const float*)d_in[10],
        (const float*)d_in[11], (const float*)d_in[12],
        (const float*)d_in[13], (const float*)d_in[14],
        (const float*)d_in[15], (const float*)d_in[16],
        (const float*)d_in[17], (const float*)d_in[18],
        (const float*)d_in[19], (const float*)d_in[20],
        (const float*)d_in[21], (const float*)d_in[22],
        (const float*)d_in[23], (const float*)d_in[24],
        out);
}

// Round 15
// 173.317 us; speedup vs baseline: 1.9201x; 1.0060x over previous
//
#include <hip/hip_runtime.h>
#include <hip/hip_bf16.h>

// BloodFlowSkinAnalyzer — f32 in/out (verified r5). Out layout (floats):
//   flow[4]@0, sync[4]@4, color[4*64*3]@8, masks[4,64,1,128,128]@776,
//   naturalness[4]@4195080, temporal[4,32,64]@4195084
// ws: colsum[4096][4] floats @0.
// Both seg convs on MFMA bf16 16x16x32 (operand layouts HW-verified r7/r8).
// r15: r14 + h1 stride 40->32 (LDS 30.5->25.7KB -> 6 blocks/CU, +20% waves;
//      accepts ~8-way conv2-read bank conflicts, proven off-critical-path in
//      r13). Arithmetic identical -> absmax must stay exactly 0.00390625.

typedef __attribute__((ext_vector_type(8))) short bf16x8;
typedef __attribute__((ext_vector_type(4))) float f32x4;

#define NAT_OFF  4195080
#define TF_OFF   4195084

__device__ __forceinline__ unsigned short f2bf(float f) {   // RNE f32->bf16
    unsigned u = __float_as_uint(f);
    u += 0x7FFFu + ((u >> 16) & 1u);
    return (unsigned short)(u >> 16);
}
__device__ __forceinline__ float bf2f(unsigned short u) {
    return __uint_as_float((unsigned)u << 16);
}
__device__ __forceinline__ unsigned pack_bf2(float lo, float hi) {
    __hip_bfloat162 h2 = __float22bfloat162_rn(make_float2(lo, hi));
    return *reinterpret_cast<unsigned*>(&h2);   // .x in low 16 bits
}

// Fused seg: conv1(3->32,k3,p1) MFMA + conv2(32->16,k3,p1) MFMA +
// conv3(16->1,k1)+sigmoid + masked sums. Block = 4 of 64 16x16 tiles.
__global__ __launch_bounds__(256) void seg_kernel(
    const float* __restrict__ x,
    const float* __restrict__ w1f, const float* __restrict__ b1f,
    const float* __restrict__ w2f, const float* __restrict__ b2f,
    const float* __restrict__ w3f, const float* __restrict__ b3f,
    float* __restrict__ colsum, float* __restrict__ out)
{
    const int tid  = threadIdx.x;
    const int lane = tid & 63;
    const int wid  = tid >> 6;
    const int img  = blockIdx.x >> 4;        // b*64+t
    const int part = blockIdx.x & 15;        // 4 tiles per part

    __shared__ __align__(4)  unsigned short in_bs[2][1200]; // dbuf 3x20x20 bf16
    __shared__ __align__(16) unsigned short h1_s[10368];    // [(y*18+x)*32+oc]
    __shared__ float red[4][4];

    const int ocl = lane & 15;   // free idx
    const int g   = lane >> 4;   // k-group (8 k's each)

    // ---- conv1 B-frags (k = ic*9+ky*3+kx, w1 native [oc][k]); k>=27 -> 0 ----
    bf16x8 c1b0, c1b1;
    int offB[8];                 // per-lane in_bs element offsets for A gather
#pragma unroll
    for (int e = 0; e < 8; ++e) {
        int k = g * 8 + e;
        if (k < 27) {
            int ic = k / 9, r2 = k - ic * 9, ky = r2 / 3, kx = r2 - ky * 3;
            offB[e] = ic * 400 + ky * 20 + kx;
            c1b0[e] = (short)f2bf(w1f[(2 * ocl)     * 27 + k]);
            c1b1[e] = (short)f2bf(w1f[(2 * ocl + 1) * 27 + k]);
        } else {
            offB[e] = 0;
            c1b0[e] = 0; c1b1[e] = 0;
        }
    }
    const float b1_e = b1f[2 * ocl], b1_o = b1f[2 * ocl + 1];

    // ---- conv2 W-frags (MFMA A operand after swap) ----
    bf16x8 bfrag[9];
#pragma unroll
    for (int c = 0; c < 9; ++c) {
        bf16x8 t;
#pragma unroll
        for (int e = 0; e < 8; ++e)
            t[e] = (short)f2bf(w2f[(ocl * 32 + g * 8 + e) * 9 + c]);
        bfrag[c] = t;
    }
    // conv3 per-lane constants for oc = g*4+r (D rows after swap)
    float b2v[4], w3v[4];
#pragma unroll
    for (int r = 0; r < 4; ++r) { b2v[r] = b2f[g * 4 + r]; w3v[r] = w3f[g * 4 + r]; }
    const float b3v = b3f[0];

    const float* xin = x + (size_t)img * 3 * 16384;
    float s0 = 0.f, s1 = 0.f, s2 = 0.f, sm = 0.f;

    // ---- prologue: stage tile 0 into buffer 0 ----
    {
        const int tile0 = part * 4;
        const int r0 = (tile0 >> 3) * 16, c0 = (tile0 & 7) * 16;
        for (int idx = tid; idx < 1200; idx += 256) {
            int ic = idx / 400, rem = idx - ic * 400;
            int r = rem / 20, cc = rem - r * 20;
            int gr = r0 - 2 + r, gc = c0 - 2 + cc;
            float vv = 0.f;
            if ((unsigned)gr < 128u && (unsigned)gc < 128u)
                vv = xin[ic * 16384 + gr * 128 + gc];
            in_bs[0][idx] = f2bf(vv);
        }
    }
    __syncthreads();

    for (int tt = 0; tt < 4; ++tt) {
        const int cur = tt & 1;
        const unsigned short* inb = in_bs[cur];
        const int tile = part * 4 + tt;
        const int r0 = (tile >> 3) * 16, c0 = (tile & 7) * 16;
        const bool interior = (r0 >= 16 && r0 <= 96 && c0 >= 16 && c0 <= 96);

        // ---- issue next tile's loads NOW (latency hides under conv1+conv2).
        float nv[5];
        if (tt < 3) {
            const int tn = tile + 1;
            const int r0n = (tn >> 3) * 16, c0n = (tn & 7) * 16;
#pragma unroll
            for (int s = 0; s < 5; ++s) {
                int idx = tid + 256 * s;
                nv[s] = 0.f;
                if (idx < 1200) {
                    int ic = idx / 400, rem = idx - ic * 400;
                    int r = rem / 20, cc = rem - r * 20;
                    int gr = r0n - 2 + r, gc = c0n - 2 + cc;
                    if ((unsigned)gr < 128u && (unsigned)gc < 128u)
                        nv[s] = xin[ic * 16384 + gr * 128 + gc];
                }
            }
        }

        // ---- conv1 MFMA: 21 groups of 16 positions over 4 waves ----
        for (int grp = wid; grp < 21; grp += 4) {
            int pos = grp * 16 + ocl;                 // A row
            int hy = pos / 18, hx = pos - hy * 18;
            int base = hy * 20 + hx;
            base = base > 357 ? 357 : base;           // clamp tail-group lanes
            bf16x8 afrag;
#pragma unroll
            for (int e = 0; e < 8; ++e)
                afrag[e] = (short)inb[base + offB[e]];
            f32x4 d0 = {0.f, 0.f, 0.f, 0.f}, d1 = {0.f, 0.f, 0.f, 0.f};
            d0 = __builtin_amdgcn_mfma_f32_16x16x32_bf16(afrag, c1b0, d0, 0, 0, 0);
            d1 = __builtin_amdgcn_mfma_f32_16x16x32_bf16(afrag, c1b1, d1, 0, 0, 0);
            int p0 = grp * 16 + g * 4;
            if (interior) {
#pragma unroll
                for (int r = 0; r < 4; ++r) {
                    int p2 = p0 + r;
                    if (p2 < 324) {
                        unsigned pk = pack_bf2(fmaxf(d0[r] + b1_e, 0.f),
                                               fmaxf(d1[r] + b1_o, 0.f));
                        *reinterpret_cast<unsigned*>(&h1_s[p2 * 32 + 2 * ocl]) = pk;
                    }
                }
            } else {
                int hy2 = p0 / 18, hx2 = p0 - hy2 * 18;
#pragma unroll
                for (int r = 0; r < 4; ++r) {
                    int p2 = p0 + r;
                    if (p2 < 324) {
                        bool valid = ((unsigned)(r0 - 1 + hy2) < 128u) &&
                                     ((unsigned)(c0 - 1 + hx2) < 128u);
                        float he = valid ? fmaxf(d0[r] + b1_e, 0.f) : 0.f;
                        float ho = valid ? fmaxf(d1[r] + b1_o, 0.f) : 0.f;
                        *reinterpret_cast<unsigned*>(&h1_s[p2 * 32 + 2 * ocl]) =
                            pack_bf2(he, ho);
                    }
                    ++hx2;
                    if (hx2 == 18) { hx2 = 0; ++hy2; }
                }
            }
        }
        __syncthreads();

        // ---- conv2: swapped operands (A=weights, B=h1) -> D[oc][x].
        //      Row-reuse: 18 b128 reads; per-q accumulation order fixed.
        const unsigned short* hb = &h1_s[((wid * 4) * 18 + ocl) * 32 + g * 8];
        f32x4 acc4[4];
#pragma unroll
        for (int q = 0; q < 4; ++q) acc4[q] = (f32x4){0.f, 0.f, 0.f, 0.f};
#pragma unroll
        for (int rp = 0; rp < 6; ++rp) {
            bf16x8 fr0 = *reinterpret_cast<const bf16x8*>(hb + (rp * 18 + 0) * 32);
            bf16x8 fr1 = *reinterpret_cast<const bf16x8*>(hb + (rp * 18 + 1) * 32);
            bf16x8 fr2 = *reinterpret_cast<const bf16x8*>(hb + (rp * 18 + 2) * 32);
#pragma unroll
            for (int ky = 0; ky < 3; ++ky) {
                const int q = rp - ky;
                if (q >= 0 && q < 4) {
                    acc4[q] = __builtin_amdgcn_mfma_f32_16x16x32_bf16(
                        bfrag[ky * 3 + 0], fr0, acc4[q], 0, 0, 0);
                    acc4[q] = __builtin_amdgcn_mfma_f32_16x16x32_bf16(
                        bfrag[ky * 3 + 1], fr1, acc4[q], 0, 0, 0);
                    acc4[q] = __builtin_amdgcn_mfma_f32_16x16x32_bf16(
                        bfrag[ky * 3 + 2], fr2, acc4[q], 0, 0, 0);
                }
            }
        }
        // conv3: lane holds P[oc=g*4+r][x=ocl]; 4 in-lane FMA + 2 shfl
#pragma unroll
        for (int q = 0; q < 4; ++q) {
            const int s = wid * 4 + q;
            float part3 = 0.f;
#pragma unroll
            for (int r = 0; r < 4; ++r)
                part3 = fmaf(fmaxf(acc4[q][r] + b2v[r], 0.f), w3v[r], part3);
            part3 += __shfl_xor(part3, 16);
            part3 += __shfl_xor(part3, 32);
            if (lane < 16) {
                int xw = lane;
                float msk = 1.f / (1.f + __expf(-(part3 + b3v)));
                out[776 + (size_t)img * 16384 + (size_t)(r0 + s) * 128 + (c0 + xw)] = msk;
                float f0  = bf2f(inb[      (s + 2) * 20 + (xw + 2)]);
                float f1v = bf2f(inb[400 + (s + 2) * 20 + (xw + 2)]);
                float f2v = bf2f(inb[800 + (s + 2) * 20 + (xw + 2)]);
                s0 = fmaf(msk, f0, s0);
                s1 = fmaf(msk, f1v, s1);
                s2 = fmaf(msk, f2v, s2);
                sm += msk;
            }
        }

        // ---- write next tile's halo into the other buffer ----
        if (tt < 3) {
#pragma unroll
            for (int s = 0; s < 5; ++s) {
                int idx = tid + 256 * s;
                if (idx < 1200) in_bs[cur ^ 1][idx] = f2bf(nv[s]);
            }
        }
        __syncthreads();
    }

    // ---- block reduction of the 4 sums ----
#pragma unroll
    for (int off = 32; off > 0; off >>= 1) {
        s0 += __shfl_down(s0, off);
        s1 += __shfl_down(s1, off);
        s2 += __shfl_down(s2, off);
        sm += __shfl_down(sm, off);
    }
    if (lane == 0) { red[wid][0] = s0; red[wid][1] = s1; red[wid][2] = s2; red[wid][3] = sm; }
    __syncthreads();
    if (tid < 4) {
        float s = red[0][tid] + red[1][tid] + red[2][tid] + red[3][tid];
        colsum[(size_t)blockIdx.x * 4 + tid] = s;   // [img][part][4]
    }
}

// Tail: 1024 threads; ta2/ta3 vectorized (b128 + lane-shfl conv halo).
__global__ __launch_bounds__(1024) void tail_kernel(
    const float* __restrict__ colsum,
    const float* __restrict__ cw1, const float* __restrict__ cb1,
    const float* __restrict__ cw2, const float* __restrict__ cb2,
    const float* __restrict__ cw3, const float* __restrict__ cb3,
    const float* __restrict__ tw1, const float* __restrict__ tb1,
    const float* __restrict__ tw2, const float* __restrict__ tb2,
    const float* __restrict__ tw3, const float* __restrict__ tb3,
    const float* __restrict__ fw1, const float* __restrict__ fb1,
    const float* __restrict__ fw2, const float* __restrict__ fb2,
    const float* __restrict__ fw3, const float* __restrict__ fb3,
    float* __restrict__ out)
{
    const int b = blockIdx.x, tid = threadIdx.x;
    __shared__ float tmp[64][4];
    __shared__ float cs_s[3 * 64];
    __shared__ float e3s[3 * 64];
    __shared__ __align__(16) float f1[32 * 64];
    __shared__ __align__(16) float f2[64 * 64];
    __shared__ __align__(16) float tf[32 * 64];
    __shared__ float pooled[32], g1[64], g2[32], sca[8];

    if (tid < 256) {
        int t = tid >> 2, slot = tid & 3;
        const float* pp = colsum + (size_t)((b * 64 + t) * 16) * 4 + slot;
        float s = 0.f;
#pragma unroll
        for (int p = 0; p < 16; ++p) s += pp[p * 4];
        tmp[t][slot] = s;
    }
    __syncthreads();
    if (tid < 192) {
        int c = tid >> 6, t = tid & 63;
        float v = tmp[t][c] / (tmp[t][3] + 1e-8f);
        cs_s[tid] = v;
        out[8 + (b * 64 + t) * 3 + c] = v;
    }
    __syncthreads();

    if (tid < 64) {
        int t = tid;
        float c0v = cs_s[t], c1v = cs_s[64 + t], c2v = cs_s[128 + t];
        float e1[16];
#pragma unroll
        for (int o = 0; o < 16; ++o)
            e1[o] = fmaxf(cb1[o] + cw1[o * 3 + 0] * c0v + cw1[o * 3 + 1] * c1v
                                 + cw1[o * 3 + 2] * c2v, 0.f);
        float e2[8];
#pragma unroll
        for (int o = 0; o < 8; ++o) {
            float a = cb2[o];
#pragma unroll
            for (int i2 = 0; i2 < 16; ++i2) a += cw2[o * 16 + i2] * e1[i2];
            e2[o] = fmaxf(a, 0.f);
        }
#pragma unroll
        for (int o = 0; o < 3; ++o) {
            float a = cb3[o];
#pragma unroll
            for (int i2 = 0; i2 < 8; ++i2) a += cw3[o * 8 + i2] * e2[i2];
            e3s[o * 64 + t] = a;   // no relu on last ct conv
        }
    }
    __syncthreads();

    // ta1: 3->32 k3 p1
    {
        int o = tid >> 6, t = tid & 63;
#pragma unroll
        for (int h = 0; h < 2; ++h) {
            int oo = o + 16 * h;
            float a = tb1[oo];
#pragma unroll
            for (int ic = 0; ic < 3; ++ic)
#pragma unroll
                for (int k = 0; k < 3; ++k) {
                    int ttk = t + k - 1;
                    if ((unsigned)ttk < 64u)
                        a += e3s[ic * 64 + ttk] * tw1[(oo * 3 + ic) * 3 + k];
                }
            f1[oo * 64 + t] = fmaxf(a, 0.f);
        }
    }
    __syncthreads();

    // ta2: 32->64 k3 p1 — thread (oo=tid>>4, t4=tid&15) computes t=4t4..4t4+3
    {
        int oo = tid >> 4, t4 = tid & 15;
        float a0 = tb2[oo], a1 = a0, a2 = a0, a3 = a0;
        for (int ic = 0; ic < 32; ++ic) {
            f32x4 c = *reinterpret_cast<const f32x4*>(&f1[ic * 64 + t4 * 4]);
            float pm = __shfl_up(c[3], 1);
            float pp = __shfl_down(c[0], 1);
            if (t4 == 0)  pm = 0.f;          // t-1 < 0 pad
            if (t4 == 15) pp = 0.f;          // t+1 > 63 pad
            const float* wp = tw2 + (oo * 32 + ic) * 3;
            float w0 = wp[0], w1 = wp[1], w2 = wp[2];
            a0 = fmaf(w0, pm,   fmaf(w1, c[0], fmaf(w2, c[1], a0)));
            a1 = fmaf(w0, c[0], fmaf(w1, c[1], fmaf(w2, c[2], a1)));
            a2 = fmaf(w0, c[1], fmaf(w1, c[2], fmaf(w2, c[3], a2)));
            a3 = fmaf(w0, c[2], fmaf(w1, c[3], fmaf(w2, pp,   a3)));
        }
        f32x4 r = {fmaxf(a0, 0.f), fmaxf(a1, 0.f), fmaxf(a2, 0.f), fmaxf(a3, 0.f)};
        *reinterpret_cast<f32x4*>(&f2[oo * 64 + t4 * 4]) = r;
    }
    __syncthreads();

    // ta3: 64->32 k3 p1 (+ temporal_features out), threads 0..511
    if (tid < 512) {
        int oo = tid >> 4, t4 = tid & 15;
        float a0 = tb3[oo], a1 = a0, a2 = a0, a3 = a0;
        for (int ic = 0; ic < 64; ++ic) {
            f32x4 c = *reinterpret_cast<const f32x4*>(&f2[ic * 64 + t4 * 4]);
            float pm = __shfl_up(c[3], 1);
            float pp = __shfl_down(c[0], 1);
            if (t4 == 0)  pm = 0.f;
            if (t4 == 15) pp = 0.f;
            const float* wp = tw3 + (oo * 64 + ic) * 3;
            float w0 = wp[0], w1 = wp[1], w2 = wp[2];
            a0 = fmaf(w0, pm,   fmaf(w1, c[0], fmaf(w2, c[1], a0)));
            a1 = fmaf(w0, c[0], fmaf(w1, c[1], fmaf(w2, c[2], a1)));
            a2 = fmaf(w0, c[1], fmaf(w1, c[2], fmaf(w2, c[3], a2)));
            a3 = fmaf(w0, c[2], fmaf(w1, c[3], fmaf(w2, pp,   a3)));
        }
        f32x4 r = {fmaxf(a0, 0.f), fmaxf(a1, 0.f), fmaxf(a2, 0.f), fmaxf(a3, 0.f)};
        *reinterpret_cast<f32x4*>(&tf[oo * 64 + t4 * 4]) = r;
        *reinterpret_cast<f32x4*>(&out[TF_OFF + (b * 32 + oo) * 64 + t4 * 4]) = r;
    }
    __syncthreads();

    if (tid < 32) {
        float s = 0.f;
#pragma unroll
        for (int t4 = 0; t4 < 16; ++t4) {
            f32x4 c = *reinterpret_cast<const f32x4*>(&tf[tid * 64 + t4 * 4]);
            s += c[0] + c[1] + c[2] + c[3];
        }
        pooled[tid] = s * (1.f / 64.f);
    }
    __syncthreads();

    if (tid < 64) {
        float a = fb1[tid];
#pragma unroll
        for (int i2 = 0; i2 < 32; ++i2) a += pooled[i2] * fw1[tid * 32 + i2];
        g1[tid] = fmaxf(a, 0.f);
    }
    __syncthreads();
    if (tid < 32) {
        float a = fb2[tid];
        for (int i2 = 0; i2 < 64; ++i2) a += g1[i2] * fw2[tid * 64 + i2];
        g2[tid] = fmaxf(a, 0.f);
    }
    __syncthreads();
    if (tid == 0) {
        float a = fb3[0];
        for (int i2 = 0; i2 < 32; ++i2) a += g2[i2] * fw3[i2];
        float flow = 1.f / (1.f + expf(-a));
        sca[0] = flow;
        out[b] = flow;
    }
    if (tid >= 4 && tid < 7) {
        int c = tid - 4;
        float mu = 0.f;
        for (int t = 0; t < 64; ++t) mu += cs_s[c * 64 + t];
        mu *= (1.f / 64.f);
        float v = 0.f;
        for (int t = 0; t < 64; ++t) { float d = cs_s[c * 64 + t] - mu; v += d * d; }
        sca[1 + c] = sqrtf(v / 63.f);
    }
    __syncthreads();
    if (tid == 0) {
        float s0 = sca[1], s1 = sca[2], s2 = sca[3];
        float mu = (s0 + s1 + s2) * (1.f / 3.f);
        float var = ((s0 - mu) * (s0 - mu) + (s1 - mu) * (s1 - mu) + (s2 - mu) * (s2 - mu)) * 0.5f;
        float sy = 1.f / (1.f + expf(var));     // sigmoid(-var)
        out[4 + b] = sy;
        out[NAT_OFF + b] = (sca[0] + sy) * 0.5f;
    }
}

extern "C" void kernel_launch(void* const* d_in, const int* in_sizes, int n_in,
                              void* d_out, int out_size, void* d_ws, size_t ws_size,
                              hipStream_t stream)
{
    float* wsf = (float*)d_ws;
    float* out = (float*)d_out;

    seg_kernel<<<dim3(4096), 256, 0, stream>>>((const float*)d_in[0],
        (const float*)d_in[1], (const float*)d_in[2],
        (const float*)d_in[3], (const float*)d_in[4],
        (const float*)d_in[5], (const float*)d_in[6],
        wsf, out);

    tail_kernel<<<dim3(4), 1024, 0, stream>>>(wsf,
        (const float*)d_in[7],  (const float*)d_in[8],
        (const float*)d_in[9],  (const float*)d_in[10],
        (const float*)d_in[11], (const float*)d_in[12],
        (const float*)d_in[13], (const float*)d_in[14],
        (const float*)d_in[15], (const float*)d_in[16],
        (const float*)d_in[17], (const float*)d_in[18],
        (const float*)d_in[19], (const float*)d_in[20],
        (const float*)d_in[21], (const float*)d_in[22],
        (const float*)d_in[23], (const float*)d_in[24],
        out);
}